// Round 4
// baseline (17631.644 us; speedup 1.0000x reference)
//
#include <hip/hip_runtime.h>
#include <hip/hip_bf16.h>
#include <math.h>

#define DIM 768
#define HEADS 12
#define HD 64
#define BB 8
#define NN 1024
#define EPSV 1e-5f

// ---------------- LayerNorm: one block (256 thr) per row of 768 ----------------
__global__ __launch_bounds__(256) void ln_kernel(const float* __restrict__ in,
                                                 const float* __restrict__ g,
                                                 const float* __restrict__ b,
                                                 float* __restrict__ out) {
    int r = blockIdx.x;
    const float* x = in + (size_t)r * DIM;
    float* o = out + (size_t)r * DIM;
    int t = threadIdx.x;
    float v0 = x[t], v1 = x[t + 256], v2 = x[t + 512];
    float s = v0 + v1 + v2;
    float s2 = v0 * v0 + v1 * v1 + v2 * v2;
    for (int off = 32; off; off >>= 1) {
        s += __shfl_xor(s, off);
        s2 += __shfl_xor(s2, off);
    }
    __shared__ float ls[4], lq[4];
    int wid = t >> 6;
    if ((t & 63) == 0) { ls[wid] = s; lq[wid] = s2; }
    __syncthreads();
    s = ls[0] + ls[1] + ls[2] + ls[3];
    s2 = lq[0] + lq[1] + lq[2] + lq[3];
    float mean = s * (1.0f / DIM);
    float var = s2 * (1.0f / DIM) - mean * mean;
    float rs = rsqrtf(var + EPSV);
    o[t]       = (v0 - mean) * rs * g[t]       + b[t];
    o[t + 256] = (v1 - mean) * rs * g[t + 256] + b[t + 256];
    o[t + 512] = (v2 - mean) * rs * g[t + 512] + b[t + 512];
}

// ---------------- fp32 GEMM: C[M,N] = A[M,K] @ W[K,N] (+bias)(+gelu)(+res) ------
// 64x64 tile per 256-thread block, K-tile 16. A staged transposed in LDS.
// res may alias C (each element is read-then-written by its unique owner thread).
template <int ACT>  // 0 = none, 1 = exact GELU
__global__ __launch_bounds__(256) void gemm_kernel(const float* __restrict__ A,
                                                   const float* __restrict__ W,
                                                   const float* __restrict__ bias,
                                                   const float* res,
                                                   float* C,
                                                   int M, int N, int K) {
    __shared__ float As[16][64];  // [k][m]
    __shared__ float Ws[16][64];  // [k][n]
    int nblk = N >> 6;
    int bx = blockIdx.x % nblk;
    int by = blockIdx.x / nblk;
    int n0 = bx * 64, m0 = by * 64;
    int tid = threadIdx.x;
    int tx = tid & 15, ty = tid >> 4;
    int arow = tid >> 2, acol = (tid & 3) * 4;
    int wrow = tid >> 4, wcol = (tid & 15) * 4;

    float acc[4][4] = {};
    for (int k0 = 0; k0 < K; k0 += 16) {
        float4 av = *(const float4*)(A + (size_t)(m0 + arow) * K + k0 + acol);
        float4 wv = *(const float4*)(W + (size_t)(k0 + wrow) * N + n0 + wcol);
        __syncthreads();
        As[acol + 0][arow] = av.x;
        As[acol + 1][arow] = av.y;
        As[acol + 2][arow] = av.z;
        As[acol + 3][arow] = av.w;
        *(float4*)&Ws[wrow][wcol] = wv;
        __syncthreads();
#pragma unroll
        for (int kk = 0; kk < 16; kk++) {
            float4 a = *(const float4*)&As[kk][ty * 4];
            float4 bv = *(const float4*)&Ws[kk][tx * 4];
            float ar[4] = {a.x, a.y, a.z, a.w};
            float br[4] = {bv.x, bv.y, bv.z, bv.w};
#pragma unroll
            for (int i = 0; i < 4; i++)
#pragma unroll
                for (int j = 0; j < 4; j++) acc[i][j] += ar[i] * br[j];
        }
    }
#pragma unroll
    for (int i = 0; i < 4; i++) {
        int m = m0 + ty * 4 + i;
        float vals[4];
#pragma unroll
        for (int j = 0; j < 4; j++) {
            int n = n0 + tx * 4 + j;
            float v = acc[i][j];
            if (bias) v += bias[n];
            if (ACT == 1) v = 0.5f * v * (1.0f + erff(v * 0.70710678118654752f));
            if (res) v += res[(size_t)m * N + n];
            vals[j] = v;
        }
        float4 o = {vals[0], vals[1], vals[2], vals[3]};
        *(float4*)(C + (size_t)m * N + n0 + tx * 4) = o;
    }
}

// ---------------- RoPE2D, in place on [N,rowStride] with heads at h*64 ----------
// half 0: dims 0..31 rotated by pos[...,0]; half 1: dims 32..63 by pos[...,1].
__global__ __launch_bounds__(256) void rope_kernel(float* __restrict__ t,
                                                   const int* __restrict__ pos,
                                                   int rowStride, int total) {
    int idx = blockIdx.x * blockDim.x + threadIdx.x;
    if (idx >= total) return;
    int i = idx & 15;
    int half = (idx >> 4) & 1;
    int h = (idx >> 5) % HEADS;
    int bn = idx / (HEADS * 32);
    int p = pos[(size_t)bn * 2 + half];
    float inv = powf(100.0f, -(float)i / 16.0f);
    float f = (float)p * inv;
    float c, s;
    sincosf(f, &s, &c);
    float* base = t + (size_t)bn * rowStride + h * HD + half * 32;
    float t1 = base[i], t2 = base[i + 16];
    base[i]      = t1 * c - t2 * s;
    base[i + 16] = t2 * c + t1 * s;
}

// ---------------- Attention (single batch): one wave per query row --------------
// grid = HEADS * (NN/4); pointers pre-offset to the batch.
__global__ __launch_bounds__(256) void attn_kernel(const float* __restrict__ Q, int sq,
                                                   const float* __restrict__ K, int sk,
                                                   const float* __restrict__ V, int sv,
                                                   float* __restrict__ O) {
    int tid = threadIdx.x;
    int lane = tid & 63, wid = tid >> 6;
    int bid = blockIdx.x;
    int nblk = bid & 255;       // NN/4 = 256 blocks per head
    int h = bid >> 8;           // 0..HEADS-1
    int n = nblk * 4 + wid;

    float qv = Q[(size_t)n * sq + h * HD + lane] * 0.125f;
    const float* Kp = K + h * HD + lane;
    const float* Vp = V + h * HD + lane;

    float m = -1e30f, l = 0.0f, acc = 0.0f;
    for (int kk = 0; kk < NN; kk++) {
        float kv = Kp[(size_t)kk * sk];
        float vv = Vp[(size_t)kk * sv];
        float s = qv * kv;
        for (int off = 32; off; off >>= 1) s += __shfl_xor(s, off);
        float mn = fmaxf(m, s);
        float corr = __expf(m - mn);
        float p = __expf(s - mn);
        l = l * corr + p;
        acc = acc * corr + p * vv;
        m = mn;
    }
    O[(size_t)n * DIM + h * HD + lane] = acc / l;
}

// ---------------- sentinel fill -------------------------------------------------
__global__ __launch_bounds__(256) void fill_f32(float* __restrict__ out, float v, int n) {
    int i = blockIdx.x * 256 + threadIdx.x;
    if (i < n) out[i] = v;
}

extern "C" void kernel_launch(void* const* d_in, const int* in_sizes, int n_in,
                              void* d_out, int out_size, void* d_ws, size_t ws_size,
                              hipStream_t stream) {
    const float* x = (const float*)d_in[0];
    const float* y = (const float*)d_in[1];
    const int* xpos = (const int*)d_in[2];
    const int* ypos = (const int*)d_in[3];
    const float* norm1_g = (const float*)d_in[4];
    const float* norm1_b = (const float*)d_in[5];
    const float* norm2_g = (const float*)d_in[6];
    const float* norm2_b = (const float*)d_in[7];
    const float* norm3_g = (const float*)d_in[8];
    const float* norm3_b = (const float*)d_in[9];
    const float* normy_g = (const float*)d_in[10];
    const float* normy_b = (const float*)d_in[11];
    const float* qkv_w = (const float*)d_in[12];
    const float* attn_proj_w = (const float*)d_in[13];
    const float* attn_proj_b = (const float*)d_in[14];
    const float* projq_w = (const float*)d_in[15];
    const float* projk_w = (const float*)d_in[16];
    const float* projv_w = (const float*)d_in[17];
    const float* cross_proj_w = (const float*)d_in[18];
    const float* cross_proj_b = (const float*)d_in[19];
    const float* fc1_w = (const float*)d_in[20];
    const float* fc1_b = (const float*)d_in[21];
    const float* fc2_w = (const float*)d_in[22];
    const float* fc2_b = (const float*)d_in[23];
    float* out = (float*)d_out;   // fp32 output: [x (SZ), y (SZ)]

    const size_t SZ  = (size_t)BB * NN * DIM;  // 6291456
    const size_t SZb = (size_t)NN * DIM;       // 786432

    // ---- interface sentinels: any mismatch -> distinctive fill, then return ----
    {
        const int expect[24] = {
            (int)SZ, (int)SZ, BB * NN * 2, BB * NN * 2,
            DIM, DIM, DIM, DIM, DIM, DIM, DIM, DIM,
            DIM * 3 * DIM, DIM * DIM, DIM,
            DIM * DIM, DIM * DIM, DIM * DIM, DIM * DIM, DIM,
            DIM * 4 * DIM, 4 * DIM, 4 * DIM * DIM, DIM};
        float sentinel = 0.0f;
        if (n_in != 24) sentinel = 2000.0f;
        else {
            for (int i = 0; i < 24; i++)
                if (in_sizes[i] != expect[i]) { sentinel = 1000.0f + i; break; }
        }
        if (sentinel == 0.0f && ws_size < (SZ + 5 * SZb) * sizeof(float)) sentinel = 3000.0f;
        if (sentinel == 0.0f && out_size != (int)(2 * SZ)) sentinel = 4000.0f;
        if (sentinel != 0.0f) {
            int n = (int)SZ;
            fill_f32<<<(n + 255) / 256, 256, 0, stream>>>(out, sentinel, n);
            return;
        }
    }

    // Workspace (floats), total = SZ + 5*SZb = 40.9 MB:
    //   bufX: SZ   running fp32 residual   | Ab: SZb  LN/attn scratch
    //   S2:  4*SZb qkv / cross qkvy / MLP hidden
    float* ws = (float*)d_ws;
    float* bufX = ws;
    float* Ab = bufX + SZ;
    float* S2 = Ab + SZb;

    const int rt = NN * HEADS * 32;  // 393216 rope threads per batch

    // ---- self attention (per batch); out-proj reads residual from input x ----
    for (int b = 0; b < BB; b++) {
        const float* xb = x + (size_t)b * SZb;
        const int* pb = xpos + (size_t)b * NN * 2;
        float* qkv = S2;  // [1024, 2304]
        ln_kernel<<<NN, 256, 0, stream>>>(xb, norm1_g, norm1_b, Ab);
        gemm_kernel<0><<<16 * 36, 256, 0, stream>>>(Ab, qkv_w, nullptr, nullptr, qkv,
                                                    NN, 3 * DIM, DIM);
        rope_kernel<<<rt / 256, 256, 0, stream>>>(qkv, pb, 3 * DIM, rt);
        rope_kernel<<<rt / 256, 256, 0, stream>>>(qkv + DIM, pb, 3 * DIM, rt);
        attn_kernel<<<HEADS * (NN / 4), 256, 0, stream>>>(
            qkv, 3 * DIM, qkv + DIM, 3 * DIM, qkv + 2 * DIM, 3 * DIM, Ab);
        gemm_kernel<0><<<16 * 12, 256, 0, stream>>>(
            Ab, attn_proj_w, attn_proj_b, xb, bufX + (size_t)b * SZb, NN, DIM, DIM);
    }

    // ---- cross attention (per batch) ----
    for (int b = 0; b < BB; b++) {
        const int* pxb = xpos + (size_t)b * NN * 2;
        const int* pyb = ypos + (size_t)b * NN * 2;
        float* Yb = S2;
        float* Qb = S2 + SZb;
        float* Kb = S2 + 2 * SZb;
        float* Vb = S2 + 3 * SZb;
        ln_kernel<<<NN, 256, 0, stream>>>(bufX + (size_t)b * SZb, norm2_g, norm2_b, Ab);
        ln_kernel<<<NN, 256, 0, stream>>>(y + (size_t)b * SZb, normy_g, normy_b, Yb);
        gemm_kernel<0><<<16 * 12, 256, 0, stream>>>(Ab, projq_w, nullptr, nullptr, Qb,
                                                    NN, DIM, DIM);
        gemm_kernel<0><<<16 * 12, 256, 0, stream>>>(Yb, projk_w, nullptr, nullptr, Kb,
                                                    NN, DIM, DIM);
        gemm_kernel<0><<<16 * 12, 256, 0, stream>>>(Yb, projv_w, nullptr, nullptr, Vb,
                                                    NN, DIM, DIM);
        rope_kernel<<<rt / 256, 256, 0, stream>>>(Qb, pxb, DIM, rt);
        rope_kernel<<<rt / 256, 256, 0, stream>>>(Kb, pyb, DIM, rt);
        attn_kernel<<<HEADS * (NN / 4), 256, 0, stream>>>(Qb, DIM, Kb, DIM, Vb, DIM, Ab);
        gemm_kernel<0><<<16 * 12, 256, 0, stream>>>(
            Ab, cross_proj_w, cross_proj_b, bufX + (size_t)b * SZb,
            bufX + (size_t)b * SZb, NN, DIM, DIM);
    }

    // ---- MLP (per batch); fc2 writes final x directly into out slot ----
    for (int b = 0; b < BB; b++) {
        float* Xch = bufX + (size_t)b * SZb;
        float* HID = S2;  // [1024, 3072] = 4*SZb
        ln_kernel<<<NN, 256, 0, stream>>>(Xch, norm3_g, norm3_b, Ab);
        gemm_kernel<1><<<16 * 48, 256, 0, stream>>>(Ab, fc1_w, fc1_b, nullptr, HID,
                                                    NN, 4 * DIM, DIM);
        gemm_kernel<0><<<16 * 12, 256, 0, stream>>>(HID, fc2_w, fc2_b, Xch,
                                                    out + (size_t)b * SZb,
                                                    NN, DIM, 4 * DIM);
    }

    // ---- output y: exact fp32 passthrough ----
    hipMemcpyAsync(out + SZ, y, SZ * sizeof(float), hipMemcpyDeviceToDevice, stream);
}

// Round 5
// 2978.069 us; speedup vs baseline: 5.9205x; 5.9205x over previous
//
#include <hip/hip_runtime.h>
#include <hip/hip_bf16.h>
#include <math.h>

#define DIM 768
#define HEADS 12
#define HD 64
#define BB 8
#define NN 1024
#define EPSV 1e-5f
#define QBLK 64
#define KBLK 64
#define PAD 68

// ---------------- LayerNorm: one block (256 thr) per row of 768 ----------------
__global__ __launch_bounds__(256) void ln_kernel(const float* __restrict__ in,
                                                 const float* __restrict__ g,
                                                 const float* __restrict__ b,
                                                 float* __restrict__ out) {
    int r = blockIdx.x;
    const float* x = in + (size_t)r * DIM;
    float* o = out + (size_t)r * DIM;
    int t = threadIdx.x;
    float v0 = x[t], v1 = x[t + 256], v2 = x[t + 512];
    float s = v0 + v1 + v2;
    float s2 = v0 * v0 + v1 * v1 + v2 * v2;
    for (int off = 32; off; off >>= 1) {
        s += __shfl_xor(s, off);
        s2 += __shfl_xor(s2, off);
    }
    __shared__ float ls[4], lq[4];
    int wid = t >> 6;
    if ((t & 63) == 0) { ls[wid] = s; lq[wid] = s2; }
    __syncthreads();
    s = ls[0] + ls[1] + ls[2] + ls[3];
    s2 = lq[0] + lq[1] + lq[2] + lq[3];
    float mean = s * (1.0f / DIM);
    float var = s2 * (1.0f / DIM) - mean * mean;
    float rs = rsqrtf(var + EPSV);
    o[t]       = (v0 - mean) * rs * g[t]       + b[t];
    o[t + 256] = (v1 - mean) * rs * g[t + 256] + b[t + 256];
    o[t + 512] = (v2 - mean) * rs * g[t + 512] + b[t + 512];
}

// ---------------- fp32 GEMM: C[M,N] = A[M,K] @ W[K,N] (+bias)(+gelu)(+res) ------
template <int ACT>  // 0 = none, 1 = exact GELU
__global__ __launch_bounds__(256) void gemm_kernel(const float* __restrict__ A,
                                                   const float* __restrict__ W,
                                                   const float* __restrict__ bias,
                                                   const float* res,
                                                   float* C,
                                                   int M, int N, int K) {
    __shared__ float As[16][64];  // [k][m]
    __shared__ float Ws[16][64];  // [k][n]
    int nblk = N >> 6;
    int bx = blockIdx.x % nblk;
    int by = blockIdx.x / nblk;
    int n0 = bx * 64, m0 = by * 64;
    int tid = threadIdx.x;
    int tx = tid & 15, ty = tid >> 4;
    int arow = tid >> 2, acol = (tid & 3) * 4;
    int wrow = tid >> 4, wcol = (tid & 15) * 4;

    float acc[4][4] = {};
    for (int k0 = 0; k0 < K; k0 += 16) {
        float4 av = *(const float4*)(A + (size_t)(m0 + arow) * K + k0 + acol);
        float4 wv = *(const float4*)(W + (size_t)(k0 + wrow) * N + n0 + wcol);
        __syncthreads();
        As[acol + 0][arow] = av.x;
        As[acol + 1][arow] = av.y;
        As[acol + 2][arow] = av.z;
        As[acol + 3][arow] = av.w;
        *(float4*)&Ws[wrow][wcol] = wv;
        __syncthreads();
#pragma unroll
        for (int kk = 0; kk < 16; kk++) {
            float4 a = *(const float4*)&As[kk][ty * 4];
            float4 bv = *(const float4*)&Ws[kk][tx * 4];
            float ar[4] = {a.x, a.y, a.z, a.w};
            float br[4] = {bv.x, bv.y, bv.z, bv.w};
#pragma unroll
            for (int i = 0; i < 4; i++)
#pragma unroll
                for (int j = 0; j < 4; j++) acc[i][j] += ar[i] * br[j];
        }
    }
#pragma unroll
    for (int i = 0; i < 4; i++) {
        int m = m0 + ty * 4 + i;
        float vals[4];
#pragma unroll
        for (int j = 0; j < 4; j++) {
            int n = n0 + tx * 4 + j;
            float v = acc[i][j];
            if (bias) v += bias[n];
            if (ACT == 1) v = 0.5f * v * (1.0f + erff(v * 0.70710678118654752f));
            if (res) v += res[(size_t)m * N + n];
            vals[j] = v;
        }
        float4 o = {vals[0], vals[1], vals[2], vals[3]};
        *(float4*)(C + (size_t)m * N + n0 + tx * 4) = o;
    }
}

// ---------------- RoPE2D (full batch), in place on [B*N, rowStride] -------------
__global__ __launch_bounds__(256) void rope_kernel(float* __restrict__ t,
                                                   const int* __restrict__ pos,
                                                   int rowStride, int total) {
    int idx = blockIdx.x * blockDim.x + threadIdx.x;
    if (idx >= total) return;
    int i = idx & 15;
    int half = (idx >> 4) & 1;
    int h = (idx >> 5) % HEADS;
    int bn = idx / (HEADS * 32);
    int p = pos[(size_t)bn * 2 + half];
    float inv = powf(100.0f, -(float)i / 16.0f);
    float f = (float)p * inv;
    float c, s;
    sincosf(f, &s, &c);
    float* base = t + (size_t)bn * rowStride + h * HD + half * 32;
    float t1 = base[i], t2 = base[i + 16];
    base[i]      = t1 * c - t2 * s;
    base[i + 16] = t2 * c + t1 * s;
}

// ---------------- Tiled flash attention (fp32), full batch ----------------------
// grid = BB*HEADS*(NN/QBLK); block 256 = 16x16 threads, 4x4 micro-tile each.
// LDS: Qs[d][i], KP (Ks[d][j] then Ps[i][j]), Vs[k][dd]; all rows padded to 68.
__global__ __launch_bounds__(256) void attn_tile(const float* __restrict__ Q, int sq,
                                                 const float* __restrict__ K, int sk,
                                                 const float* __restrict__ V, int sv,
                                                 float* __restrict__ O, int so) {
    __shared__ float Qs[HD][PAD];
    __shared__ float KP[HD][PAD];   // Ks[d][j] during QK^T, Ps[i][j] during PV
    __shared__ float Vs[KBLK][PAD];

    int bid = blockIdx.x;
    int qb = bid & 15;              // NN/QBLK = 16
    int h = (bid >> 4) % HEADS;
    int b = bid / (16 * HEADS);
    int n0 = qb * QBLK;

    int tid = threadIdx.x;
    int tx = tid & 15, ty = tid >> 4;

    const float* Qbase = Q + (size_t)b * NN * sq + h * HD;
    const float* Kbase = K + (size_t)b * NN * sk + h * HD;
    const float* Vbase = V + (size_t)b * NN * sv + h * HD;
    float* Obase = O + (size_t)b * NN * so + h * HD;

    // stage Q tile transposed: Qs[d][i] = Q[n0+i][d]
    {
        int i = tid >> 2, c0 = (tid & 3) * 16;
        const float* qrow = Qbase + (size_t)(n0 + i) * sq + c0;
#pragma unroll
        for (int u = 0; u < 4; u++) {
            float4 v = *(const float4*)(qrow + u * 4);
            Qs[c0 + u * 4 + 0][i] = v.x;
            Qs[c0 + u * 4 + 1][i] = v.y;
            Qs[c0 + u * 4 + 2][i] = v.z;
            Qs[c0 + u * 4 + 3][i] = v.w;
        }
    }

    float o[4][4] = {};
    float mrow[4] = {-1e30f, -1e30f, -1e30f, -1e30f};
    float lrow[4] = {};

    for (int kt = 0; kt < NN / KBLK; kt++) {
        __syncthreads();  // prev PV done reading Ps/Vs (and Q staging visible, iter 0)
        {   // stage K transposed, V natural
            int j = tid >> 2, c0 = (tid & 3) * 16;
            const float* krow = Kbase + (size_t)(kt * KBLK + j) * sk + c0;
#pragma unroll
            for (int u = 0; u < 4; u++) {
                float4 v = *(const float4*)(krow + u * 4);
                KP[c0 + u * 4 + 0][j] = v.x;
                KP[c0 + u * 4 + 1][j] = v.y;
                KP[c0 + u * 4 + 2][j] = v.z;
                KP[c0 + u * 4 + 3][j] = v.w;
            }
            const float* vrow = Vbase + (size_t)(kt * KBLK + j) * sv + c0;
#pragma unroll
            for (int u = 0; u < 4; u++)
                *(float4*)&Vs[j][c0 + u * 4] = *(const float4*)(vrow + u * 4);
        }
        __syncthreads();

        // S = 0.125 * Q K^T
        float s[4][4] = {};
#pragma unroll 4
        for (int d = 0; d < HD; d++) {
            float4 a = *(const float4*)&Qs[d][ty * 4];
            float4 bb = *(const float4*)&KP[d][tx * 4];
            float ar[4] = {a.x, a.y, a.z, a.w};
            float br[4] = {bb.x, bb.y, bb.z, bb.w};
#pragma unroll
            for (int e = 0; e < 4; e++)
#pragma unroll
                for (int f = 0; f < 4; f++) s[e][f] += ar[e] * br[f];
        }

        // online softmax update (row stats across tx lanes: xor 1,2,4,8)
        float corr[4];
#pragma unroll
        for (int e = 0; e < 4; e++) {
#pragma unroll
            for (int f = 0; f < 4; f++) s[e][f] *= 0.125f;
            float rm = fmaxf(fmaxf(s[e][0], s[e][1]), fmaxf(s[e][2], s[e][3]));
            rm = fmaxf(rm, __shfl_xor(rm, 1));
            rm = fmaxf(rm, __shfl_xor(rm, 2));
            rm = fmaxf(rm, __shfl_xor(rm, 4));
            rm = fmaxf(rm, __shfl_xor(rm, 8));
            float mn = fmaxf(mrow[e], rm);
            corr[e] = __expf(mrow[e] - mn);
            mrow[e] = mn;
            float ps = 0.0f;
#pragma unroll
            for (int f = 0; f < 4; f++) {
                float p = __expf(s[e][f] - mn);
                s[e][f] = p;
                ps += p;
            }
            ps += __shfl_xor(ps, 1);
            ps += __shfl_xor(ps, 2);
            ps += __shfl_xor(ps, 4);
            ps += __shfl_xor(ps, 8);
            lrow[e] = lrow[e] * corr[e] + ps;
#pragma unroll
            for (int f = 0; f < 4; f++) o[e][f] *= corr[e];
        }

        __syncthreads();  // everyone done reading Ks before overwriting with Ps
#pragma unroll
        for (int e = 0; e < 4; e++) {
            float4 pv = {s[e][0], s[e][1], s[e][2], s[e][3]};
            *(float4*)&KP[ty * 4 + e][tx * 4] = pv;
        }
        __syncthreads();  // Ps visible

        // O += P @ V
#pragma unroll 4
        for (int k = 0; k < KBLK; k++) {
            float4 vv = *(const float4*)&Vs[k][tx * 4];
            float vr[4] = {vv.x, vv.y, vv.z, vv.w};
#pragma unroll
            for (int e = 0; e < 4; e++) {
                float p = KP[ty * 4 + e][k];
#pragma unroll
                for (int f = 0; f < 4; f++) o[e][f] += p * vr[f];
            }
        }
    }

    // epilogue: normalize and write
#pragma unroll
    for (int e = 0; e < 4; e++) {
        float inv = 1.0f / lrow[e];
        float4 ov = {o[e][0] * inv, o[e][1] * inv, o[e][2] * inv, o[e][3] * inv};
        *(float4*)(Obase + (size_t)(n0 + ty * 4 + e) * so + tx * 4) = ov;
    }
}

// ---------------- sentinel fill -------------------------------------------------
__global__ __launch_bounds__(256) void fill_f32(float* __restrict__ out, float v, int n) {
    int i = blockIdx.x * 256 + threadIdx.x;
    if (i < n) out[i] = v;
}

extern "C" void kernel_launch(void* const* d_in, const int* in_sizes, int n_in,
                              void* d_out, int out_size, void* d_ws, size_t ws_size,
                              hipStream_t stream) {
    const float* x = (const float*)d_in[0];
    const float* y = (const float*)d_in[1];
    const int* xpos = (const int*)d_in[2];
    const int* ypos = (const int*)d_in[3];
    const float* norm1_g = (const float*)d_in[4];
    const float* norm1_b = (const float*)d_in[5];
    const float* norm2_g = (const float*)d_in[6];
    const float* norm2_b = (const float*)d_in[7];
    const float* norm3_g = (const float*)d_in[8];
    const float* norm3_b = (const float*)d_in[9];
    const float* normy_g = (const float*)d_in[10];
    const float* normy_b = (const float*)d_in[11];
    const float* qkv_w = (const float*)d_in[12];
    const float* attn_proj_w = (const float*)d_in[13];
    const float* attn_proj_b = (const float*)d_in[14];
    const float* projq_w = (const float*)d_in[15];
    const float* projk_w = (const float*)d_in[16];
    const float* projv_w = (const float*)d_in[17];
    const float* cross_proj_w = (const float*)d_in[18];
    const float* cross_proj_b = (const float*)d_in[19];
    const float* fc1_w = (const float*)d_in[20];
    const float* fc1_b = (const float*)d_in[21];
    const float* fc2_w = (const float*)d_in[22];
    const float* fc2_b = (const float*)d_in[23];
    float* out = (float*)d_out;   // fp32: [x (SZ), y (SZ)]

    const size_t SZ = (size_t)BB * NN * DIM;  // 6291456
    const int ROWS = BB * NN;                 // 8192

    // ---- interface sentinels ----
    {
        const int expect[24] = {
            (int)SZ, (int)SZ, BB * NN * 2, BB * NN * 2,
            DIM, DIM, DIM, DIM, DIM, DIM, DIM, DIM,
            DIM * 3 * DIM, DIM * DIM, DIM,
            DIM * DIM, DIM * DIM, DIM * DIM, DIM * DIM, DIM,
            DIM * 4 * DIM, 4 * DIM, 4 * DIM * DIM, DIM};
        float sentinel = 0.0f;
        if (n_in != 24) sentinel = 2000.0f;
        else {
            for (int i = 0; i < 24; i++)
                if (in_sizes[i] != expect[i]) { sentinel = 1000.0f + i; break; }
        }
        if (sentinel == 0.0f && ws_size < 5 * SZ * sizeof(float)) sentinel = 3000.0f;
        if (sentinel == 0.0f && out_size != (int)(2 * SZ)) sentinel = 4000.0f;
        if (sentinel != 0.0f) {
            fill_f32<<<(int)((SZ + 255) / 256), 256, 0, stream>>>(out, sentinel, (int)SZ);
            return;
        }
    }

    // ws (floats): bufX(SZ) | bufA(SZ) | bufQKV(3*SZ)  = 5*SZ = 125.8 MB
    float* ws = (float*)d_ws;
    float* bufX = ws;
    float* bufA = bufX + SZ;
    float* bufQKV = bufA + SZ;

    const int rt = ROWS * HEADS * 32;  // 3145728 rope threads (full batch)
    const int attnGrid = BB * HEADS * (NN / QBLK);  // 1536

    // ---- self attention (full batch) ----
    ln_kernel<<<ROWS, 256, 0, stream>>>(x, norm1_g, norm1_b, bufA);
    gemm_kernel<0><<<(ROWS / 64) * (3 * DIM / 64), 256, 0, stream>>>(
        bufA, qkv_w, nullptr, nullptr, bufQKV, ROWS, 3 * DIM, DIM);
    rope_kernel<<<rt / 256, 256, 0, stream>>>(bufQKV, xpos, 3 * DIM, rt);
    rope_kernel<<<rt / 256, 256, 0, stream>>>(bufQKV + DIM, xpos, 3 * DIM, rt);
    attn_tile<<<attnGrid, 256, 0, stream>>>(bufQKV, 3 * DIM, bufQKV + DIM, 3 * DIM,
                                            bufQKV + 2 * DIM, 3 * DIM, bufA, DIM);
    gemm_kernel<0><<<(ROWS / 64) * (DIM / 64), 256, 0, stream>>>(
        bufA, attn_proj_w, attn_proj_b, x, bufX, ROWS, DIM, DIM);

    // ---- cross attention (full batch) ----
    float* Qc = bufQKV;
    float* Kc = bufQKV + SZ;
    float* Vc = bufQKV + 2 * SZ;
    ln_kernel<<<ROWS, 256, 0, stream>>>(bufX, norm2_g, norm2_b, bufA);
    gemm_kernel<0><<<(ROWS / 64) * (DIM / 64), 256, 0, stream>>>(
        bufA, projq_w, nullptr, nullptr, Qc, ROWS, DIM, DIM);
    ln_kernel<<<ROWS, 256, 0, stream>>>(y, normy_g, normy_b, bufA);
    gemm_kernel<0><<<(ROWS / 64) * (DIM / 64), 256, 0, stream>>>(
        bufA, projk_w, nullptr, nullptr, Kc, ROWS, DIM, DIM);
    gemm_kernel<0><<<(ROWS / 64) * (DIM / 64), 256, 0, stream>>>(
        bufA, projv_w, nullptr, nullptr, Vc, ROWS, DIM, DIM);
    rope_kernel<<<rt / 256, 256, 0, stream>>>(Qc, xpos, DIM, rt);
    rope_kernel<<<rt / 256, 256, 0, stream>>>(Kc, ypos, DIM, rt);
    attn_tile<<<attnGrid, 256, 0, stream>>>(Qc, DIM, Kc, DIM, Vc, DIM, bufA, DIM);
    gemm_kernel<0><<<(ROWS / 64) * (DIM / 64), 256, 0, stream>>>(
        bufA, cross_proj_w, cross_proj_b, bufX, bufX, ROWS, DIM, DIM);

    // ---- MLP (2 chunks of 4096 rows; hidden reuses bufQKV) ----
    ln_kernel<<<ROWS, 256, 0, stream>>>(bufX, norm3_g, norm3_b, bufA);
    for (int c = 0; c < 2; c++) {
        size_t r0 = (size_t)c * 4096;
        float* HID = bufQKV;  // [4096, 3072] = 2*SZ, fits in 3*SZ
        gemm_kernel<1><<<(4096 / 64) * (3072 / 64), 256, 0, stream>>>(
            bufA + r0 * DIM, fc1_w, fc1_b, nullptr, HID, 4096, 4 * DIM, DIM);
        gemm_kernel<0><<<(4096 / 64) * (DIM / 64), 256, 0, stream>>>(
            HID, fc2_w, fc2_b, bufX + r0 * DIM, out + r0 * DIM, 4096, DIM, 4 * DIM);
    }

    // ---- output y passthrough ----
    hipMemcpyAsync(out + SZ, y, SZ * sizeof(float), hipMemcpyDeviceToDevice, stream);
}

// Round 6
// 1282.979 us; speedup vs baseline: 13.7427x; 2.3212x over previous
//
#include <hip/hip_runtime.h>
#include <hip/hip_bf16.h>
#include <math.h>

#define DIM 768
#define HEADS 12
#define HD 64
#define BB 8
#define NN 1024
#define EPSV 1e-5f
#define QBLK 64
#define KBLK 64
#define PAD 68

typedef unsigned int uint32;
using short8 = __attribute__((ext_vector_type(8))) short;
using f32x4 = __attribute__((ext_vector_type(4))) float;

// fp32 -> bf16 (RNE), bit-level (avoids __hip_bfloat16 type plumbing)
static __device__ inline unsigned short f2b(float v) {
    uint32 u = __float_as_uint(v);
    uint32 r = (u + 0x7FFFu + ((u >> 16) & 1u)) >> 16;
    return (unsigned short)r;
}

// ---------------- LayerNorm -> bf16: one block (256 thr) per row of 768 ---------
__global__ __launch_bounds__(256) void ln_bf16(const float* __restrict__ in,
                                               const float* __restrict__ g,
                                               const float* __restrict__ b,
                                               unsigned short* __restrict__ out) {
    int r = blockIdx.x;
    const float* x = in + (size_t)r * DIM;
    unsigned short* o = out + (size_t)r * DIM;
    int t = threadIdx.x;
    float v0 = x[t], v1 = x[t + 256], v2 = x[t + 512];
    float s = v0 + v1 + v2;
    float s2 = v0 * v0 + v1 * v1 + v2 * v2;
    for (int off = 32; off; off >>= 1) {
        s += __shfl_xor(s, off);
        s2 += __shfl_xor(s2, off);
    }
    __shared__ float ls[4], lq[4];
    int wid = t >> 6;
    if ((t & 63) == 0) { ls[wid] = s; lq[wid] = s2; }
    __syncthreads();
    s = ls[0] + ls[1] + ls[2] + ls[3];
    s2 = lq[0] + lq[1] + lq[2] + lq[3];
    float mean = s * (1.0f / DIM);
    float var = s2 * (1.0f / DIM) - mean * mean;
    float rs = rsqrtf(var + EPSV);
    o[t]       = f2b((v0 - mean) * rs * g[t]       + b[t]);
    o[t + 256] = f2b((v1 - mean) * rs * g[t + 256] + b[t + 256]);
    o[t + 512] = f2b((v2 - mean) * rs * g[t + 512] + b[t + 512]);
}

// ---------------- Weight cast+transpose: W[K][N] fp32 -> Wt[N][K] bf16 ----------
struct XArgs {
    const float* src[8];
    unsigned short* dst[8];
    int K[8], N[8];
    int tstart[9];
};
__global__ __launch_bounds__(256) void xform_w(XArgs a) {
    __shared__ float tl[32][33];
    int t = blockIdx.x;
    int w = 0;
    while (t >= a.tstart[w + 1]) w++;
    int lt = t - a.tstart[w];
    int ntn = a.N[w] >> 5;
    int k0 = (lt / ntn) * 32, n0 = (lt % ntn) * 32;
    const float* src = a.src[w];
    unsigned short* dst = a.dst[w];
    int K = a.K[w], N = a.N[w];
    int rr = threadIdx.x >> 5, cc = threadIdx.x & 31;
#pragma unroll
    for (int u = 0; u < 4; u++)
        tl[rr + u * 8][cc] = src[(size_t)(k0 + rr + u * 8) * N + n0 + cc];
    __syncthreads();
#pragma unroll
    for (int u = 0; u < 4; u++)
        dst[(size_t)(n0 + rr + u * 8) * K + k0 + cc] = f2b(tl[cc][rr + u * 8]);
}

// ---------------- bf16 MFMA GEMM: C[M,N] = A[M,K] @ Wt[N,K]^T (+bias/gelu/res) --
// 128x128 tile, 4 waves (2x2), per-wave 64x64 via 4x4 frags of 16x16x32.
template <int ACT, int OBF16>
__global__ __launch_bounds__(256) void gemm_mfma(const unsigned short* __restrict__ A,
                                                 const unsigned short* __restrict__ Wt,
                                                 const float* __restrict__ bias,
                                                 const float* res,
                                                 void* Cout, int M, int N, int K) {
    __shared__ unsigned short As[128][40];  // [m][k] pad->40: frag reads conflict-free
    __shared__ unsigned short Bs[128][40];  // [n][k]
    int nblk = N >> 7;
    int bx = blockIdx.x % nblk, by = blockIdx.x / nblk;
    int m0 = by * 128, n0 = bx * 128;
    int tid = threadIdx.x;
    int wid = tid >> 6, lane = tid & 63;
    int wm = wid >> 1, wn = wid & 1;
    int srow = tid >> 2, skoff = (tid & 3) * 8;

    const unsigned short* Abase = A + (size_t)m0 * K;
    const unsigned short* Bbase = Wt + (size_t)n0 * K;

    f32x4 acc[4][4] = {};
    for (int k0 = 0; k0 < K; k0 += 32) {
        __syncthreads();
        *(uint4*)&As[srow][skoff]      = *(const uint4*)(Abase + (size_t)srow * K + k0 + skoff);
        *(uint4*)&As[srow + 64][skoff] = *(const uint4*)(Abase + (size_t)(srow + 64) * K + k0 + skoff);
        *(uint4*)&Bs[srow][skoff]      = *(const uint4*)(Bbase + (size_t)srow * K + k0 + skoff);
        *(uint4*)&Bs[srow + 64][skoff] = *(const uint4*)(Bbase + (size_t)(srow + 64) * K + k0 + skoff);
        __syncthreads();
        int c16 = lane & 15, k8 = (lane >> 4) * 8;
        short8 af[4], bfr[4];
#pragma unroll
        for (int i = 0; i < 4; i++) {
            af[i]  = *(const short8*)&As[wm * 64 + i * 16 + c16][k8];
            bfr[i] = *(const short8*)&Bs[wn * 64 + i * 16 + c16][k8];
        }
#pragma unroll
        for (int i = 0; i < 4; i++)
#pragma unroll
            for (int j = 0; j < 4; j++)
                acc[i][j] = __builtin_amdgcn_mfma_f32_16x16x32_bf16(af[i], bfr[j],
                                                                    acc[i][j], 0, 0, 0);
    }

    // epilogue: C/D layout col=lane&15, row=(lane>>4)*4+reg  [m89 verified]
    int col = lane & 15, rg = (lane >> 4) * 4;
#pragma unroll
    for (int j = 0; j < 4; j++) {
        int n = n0 + wn * 64 + j * 16 + col;
        float bv = bias ? bias[n] : 0.0f;
#pragma unroll
        for (int i = 0; i < 4; i++) {
#pragma unroll
            for (int r = 0; r < 4; r++) {
                int m = m0 + wm * 64 + i * 16 + rg + r;
                float v = acc[i][j][r] + bv;
                if (ACT == 1) v = 0.5f * v * (1.0f + erff(v * 0.70710678118654752f));
                if (res) v += res[(size_t)m * N + n];
                if (OBF16) ((unsigned short*)Cout)[(size_t)m * N + n] = f2b(v);
                else       ((float*)Cout)[(size_t)m * N + n] = v;
            }
        }
    }
}

// ---------------- RoPE2D (full batch), in place on [B*N, rowStride] fp32 --------
__global__ __launch_bounds__(256) void rope_kernel(float* __restrict__ t,
                                                   const int* __restrict__ pos,
                                                   int rowStride, int total) {
    int idx = blockIdx.x * blockDim.x + threadIdx.x;
    if (idx >= total) return;
    int i = idx & 15;
    int half = (idx >> 4) & 1;
    int h = (idx >> 5) % HEADS;
    int bn = idx / (HEADS * 32);
    int p = pos[(size_t)bn * 2 + half];
    float inv = powf(100.0f, -(float)i / 16.0f);
    float f = (float)p * inv;
    float c, s;
    sincosf(f, &s, &c);
    float* base = t + (size_t)bn * rowStride + h * HD + half * 32;
    float t1 = base[i], t2 = base[i + 16];
    base[i]      = t1 * c - t2 * s;
    base[i + 16] = t2 * c + t1 * s;
}

// ---------------- Tiled flash attention (fp32 in, bf16 out), full batch ---------
__global__ __launch_bounds__(256) void attn_tile(const float* __restrict__ Q, int sq,
                                                 const float* __restrict__ K, int sk,
                                                 const float* __restrict__ V, int sv,
                                                 unsigned short* __restrict__ O, int so) {
    __shared__ float Qs[HD][PAD];
    __shared__ float KP[HD][PAD];
    __shared__ float Vs[KBLK][PAD];

    int bid = blockIdx.x;
    int qb = bid & 15;
    int h = (bid >> 4) % HEADS;
    int b = bid / (16 * HEADS);
    int n0 = qb * QBLK;

    int tid = threadIdx.x;
    int tx = tid & 15, ty = tid >> 4;

    const float* Qbase = Q + (size_t)b * NN * sq + h * HD;
    const float* Kbase = K + (size_t)b * NN * sk + h * HD;
    const float* Vbase = V + (size_t)b * NN * sv + h * HD;
    unsigned short* Obase = O + (size_t)b * NN * so + h * HD;

    {
        int i = tid >> 2, c0 = (tid & 3) * 16;
        const float* qrow = Qbase + (size_t)(n0 + i) * sq + c0;
#pragma unroll
        for (int u = 0; u < 4; u++) {
            float4 v = *(const float4*)(qrow + u * 4);
            Qs[c0 + u * 4 + 0][i] = v.x;
            Qs[c0 + u * 4 + 1][i] = v.y;
            Qs[c0 + u * 4 + 2][i] = v.z;
            Qs[c0 + u * 4 + 3][i] = v.w;
        }
    }

    float o[4][4] = {};
    float mrow[4] = {-1e30f, -1e30f, -1e30f, -1e30f};
    float lrow[4] = {};

    for (int kt = 0; kt < NN / KBLK; kt++) {
        __syncthreads();
        {
            int j = tid >> 2, c0 = (tid & 3) * 16;
            const float* krow = Kbase + (size_t)(kt * KBLK + j) * sk + c0;
#pragma unroll
            for (int u = 0; u < 4; u++) {
                float4 v = *(const float4*)(krow + u * 4);
                KP[c0 + u * 4 + 0][j] = v.x;
                KP[c0 + u * 4 + 1][j] = v.y;
                KP[c0 + u * 4 + 2][j] = v.z;
                KP[c0 + u * 4 + 3][j] = v.w;
            }
            const float* vrow = Vbase + (size_t)(kt * KBLK + j) * sv + c0;
#pragma unroll
            for (int u = 0; u < 4; u++)
                *(float4*)&Vs[j][c0 + u * 4] = *(const float4*)(vrow + u * 4);
        }
        __syncthreads();

        float s[4][4] = {};
#pragma unroll 4
        for (int d = 0; d < HD; d++) {
            float4 a = *(const float4*)&Qs[d][ty * 4];
            float4 bb = *(const float4*)&KP[d][tx * 4];
            float ar[4] = {a.x, a.y, a.z, a.w};
            float br[4] = {bb.x, bb.y, bb.z, bb.w};
#pragma unroll
            for (int e = 0; e < 4; e++)
#pragma unroll
                for (int f = 0; f < 4; f++) s[e][f] += ar[e] * br[f];
        }

        float corr[4];
#pragma unroll
        for (int e = 0; e < 4; e++) {
#pragma unroll
            for (int f = 0; f < 4; f++) s[e][f] *= 0.125f;
            float rm = fmaxf(fmaxf(s[e][0], s[e][1]), fmaxf(s[e][2], s[e][3]));
            rm = fmaxf(rm, __shfl_xor(rm, 1));
            rm = fmaxf(rm, __shfl_xor(rm, 2));
            rm = fmaxf(rm, __shfl_xor(rm, 4));
            rm = fmaxf(rm, __shfl_xor(rm, 8));
            float mn = fmaxf(mrow[e], rm);
            corr[e] = __expf(mrow[e] - mn);
            mrow[e] = mn;
            float ps = 0.0f;
#pragma unroll
            for (int f = 0; f < 4; f++) {
                float p = __expf(s[e][f] - mn);
                s[e][f] = p;
                ps += p;
            }
            ps += __shfl_xor(ps, 1);
            ps += __shfl_xor(ps, 2);
            ps += __shfl_xor(ps, 4);
            ps += __shfl_xor(ps, 8);
            lrow[e] = lrow[e] * corr[e] + ps;
#pragma unroll
            for (int f = 0; f < 4; f++) o[e][f] *= corr[e];
        }

        __syncthreads();
#pragma unroll
        for (int e = 0; e < 4; e++) {
            float4 pv = {s[e][0], s[e][1], s[e][2], s[e][3]};
            *(float4*)&KP[ty * 4 + e][tx * 4] = pv;
        }
        __syncthreads();

#pragma unroll 4
        for (int k = 0; k < KBLK; k++) {
            float4 vv = *(const float4*)&Vs[k][tx * 4];
            float vr[4] = {vv.x, vv.y, vv.z, vv.w};
#pragma unroll
            for (int e = 0; e < 4; e++) {
                float p = KP[ty * 4 + e][k];
#pragma unroll
                for (int f = 0; f < 4; f++) o[e][f] += p * vr[f];
            }
        }
    }

#pragma unroll
    for (int e = 0; e < 4; e++) {
        float inv = 1.0f / lrow[e];
        ushort4 ov;
        ov.x = f2b(o[e][0] * inv);
        ov.y = f2b(o[e][1] * inv);
        ov.z = f2b(o[e][2] * inv);
        ov.w = f2b(o[e][3] * inv);
        *(ushort4*)(Obase + (size_t)(n0 + ty * 4 + e) * so + tx * 4) = ov;
    }
}

// ---------------- sentinel fill -------------------------------------------------
__global__ __launch_bounds__(256) void fill_f32(float* __restrict__ out, float v, int n) {
    int i = blockIdx.x * 256 + threadIdx.x;
    if (i < n) out[i] = v;
}

extern "C" void kernel_launch(void* const* d_in, const int* in_sizes, int n_in,
                              void* d_out, int out_size, void* d_ws, size_t ws_size,
                              hipStream_t stream) {
    const float* x = (const float*)d_in[0];
    const float* y = (const float*)d_in[1];
    const int* xpos = (const int*)d_in[2];
    const int* ypos = (const int*)d_in[3];
    const float* norm1_g = (const float*)d_in[4];
    const float* norm1_b = (const float*)d_in[5];
    const float* norm2_g = (const float*)d_in[6];
    const float* norm2_b = (const float*)d_in[7];
    const float* norm3_g = (const float*)d_in[8];
    const float* norm3_b = (const float*)d_in[9];
    const float* normy_g = (const float*)d_in[10];
    const float* normy_b = (const float*)d_in[11];
    const float* qkv_w = (const float*)d_in[12];
    const float* attn_proj_w = (const float*)d_in[13];
    const float* attn_proj_b = (const float*)d_in[14];
    const float* projq_w = (const float*)d_in[15];
    const float* projk_w = (const float*)d_in[16];
    const float* projv_w = (const float*)d_in[17];
    const float* cross_proj_w = (const float*)d_in[18];
    const float* cross_proj_b = (const float*)d_in[19];
    const float* fc1_w = (const float*)d_in[20];
    const float* fc1_b = (const float*)d_in[21];
    const float* fc2_w = (const float*)d_in[22];
    const float* fc2_b = (const float*)d_in[23];
    float* out = (float*)d_out;

    const size_t SZ = (size_t)BB * NN * DIM;  // 6291456
    const int ROWS = BB * NN;                 // 8192

    // ws layout (bytes): bufX f32(SZ) | bufQKV f32(3SZ) | bufAb bf16(SZ) | wts bf16
    const size_t WS_NEED = SZ * 4 + 3 * SZ * 4 + SZ * 2 + 9437184ull * 2;  // 132,120,576

    // ---- interface sentinels ----
    {
        const int expect[24] = {
            (int)SZ, (int)SZ, BB * NN * 2, BB * NN * 2,
            DIM, DIM, DIM, DIM, DIM, DIM, DIM, DIM,
            DIM * 3 * DIM, DIM * DIM, DIM,
            DIM * DIM, DIM * DIM, DIM * DIM, DIM * DIM, DIM,
            DIM * 4 * DIM, 4 * DIM, 4 * DIM * DIM, DIM};
        float sentinel = 0.0f;
        if (n_in != 24) sentinel = 2000.0f;
        else {
            for (int i = 0; i < 24; i++)
                if (in_sizes[i] != expect[i]) { sentinel = 1000.0f + i; break; }
        }
        if (sentinel == 0.0f && ws_size < WS_NEED) sentinel = 3000.0f;
        if (sentinel == 0.0f && out_size != (int)(2 * SZ)) sentinel = 4000.0f;
        if (sentinel != 0.0f) {
            fill_f32<<<(int)((SZ + 255) / 256), 256, 0, stream>>>(out, sentinel, (int)SZ);
            return;
        }
    }

    float* bufX = (float*)d_ws;
    float* bufQKV = bufX + SZ;                       // 3*SZ f32; also HID bf16 reuse
    unsigned short* bufAb = (unsigned short*)(bufQKV + 3 * SZ);  // SZ bf16
    unsigned short* wts = bufAb + SZ;

    unsigned short* qkvT = wts;                      // [2304][768]
    unsigned short* apT  = qkvT + 2304 * 768;
    unsigned short* pqT  = apT + 768 * 768;
    unsigned short* pkT  = pqT + 768 * 768;
    unsigned short* pvT  = pkT + 768 * 768;
    unsigned short* cpT  = pvT + 768 * 768;
    unsigned short* fc1T = cpT + 768 * 768;          // [3072][768]
    unsigned short* fc2T = fc1T + 3072 * 768;        // [768][3072]
    unsigned short* HID  = (unsigned short*)bufQKV;  // [8192][3072] bf16 (MLP phase)

    // ---- one-time (per launch) weight cast+transpose ----
    XArgs xa;
    xa.src[0] = qkv_w;        xa.dst[0] = qkvT; xa.K[0] = 768;  xa.N[0] = 2304;
    xa.src[1] = attn_proj_w;  xa.dst[1] = apT;  xa.K[1] = 768;  xa.N[1] = 768;
    xa.src[2] = projq_w;      xa.dst[2] = pqT;  xa.K[2] = 768;  xa.N[2] = 768;
    xa.src[3] = projk_w;      xa.dst[3] = pkT;  xa.K[3] = 768;  xa.N[3] = 768;
    xa.src[4] = projv_w;      xa.dst[4] = pvT;  xa.K[4] = 768;  xa.N[4] = 768;
    xa.src[5] = cross_proj_w; xa.dst[5] = cpT;  xa.K[5] = 768;  xa.N[5] = 768;
    xa.src[6] = fc1_w;        xa.dst[6] = fc1T; xa.K[6] = 768;  xa.N[6] = 3072;
    xa.src[7] = fc2_w;        xa.dst[7] = fc2T; xa.K[7] = 3072; xa.N[7] = 768;
    int acc_t = 0;
    for (int i = 0; i < 8; i++) {
        xa.tstart[i] = acc_t;
        acc_t += (xa.K[i] / 32) * (xa.N[i] / 32);
    }
    xa.tstart[8] = acc_t;  // 9216
    xform_w<<<acc_t, 256, 0, stream>>>(xa);

    const int rt = ROWS * HEADS * 32;
    const int attnGrid = BB * HEADS * (NN / QBLK);

    // ---- self attention ----
    ln_bf16<<<ROWS, 256, 0, stream>>>(x, norm1_g, norm1_b, bufAb);
    gemm_mfma<0, 0><<<64 * 18, 256, 0, stream>>>(bufAb, qkvT, nullptr, nullptr,
                                                 bufQKV, ROWS, 2304, 768);
    rope_kernel<<<rt / 256, 256, 0, stream>>>(bufQKV, xpos, 2304, rt);
    rope_kernel<<<rt / 256, 256, 0, stream>>>(bufQKV + DIM, xpos, 2304, rt);
    attn_tile<<<attnGrid, 256, 0, stream>>>(bufQKV, 2304, bufQKV + DIM, 2304,
                                            bufQKV + 2 * DIM, 2304, bufAb, DIM);
    gemm_mfma<0, 0><<<64 * 6, 256, 0, stream>>>(bufAb, apT, attn_proj_b, x,
                                                bufX, ROWS, 768, 768);

    // ---- cross attention ----
    float* Qc = bufQKV;
    float* Kc = bufQKV + SZ;
    float* Vc = bufQKV + 2 * SZ;
    ln_bf16<<<ROWS, 256, 0, stream>>>(bufX, norm2_g, norm2_b, bufAb);
    gemm_mfma<0, 0><<<64 * 6, 256, 0, stream>>>(bufAb, pqT, nullptr, nullptr,
                                                Qc, ROWS, 768, 768);
    ln_bf16<<<ROWS, 256, 0, stream>>>(y, normy_g, normy_b, bufAb);
    gemm_mfma<0, 0><<<64 * 6, 256, 0, stream>>>(bufAb, pkT, nullptr, nullptr,
                                                Kc, ROWS, 768, 768);
    gemm_mfma<0, 0><<<64 * 6, 256, 0, stream>>>(bufAb, pvT, nullptr, nullptr,
                                                Vc, ROWS, 768, 768);
    rope_kernel<<<rt / 256, 256, 0, stream>>>(Qc, xpos, DIM, rt);
    rope_kernel<<<rt / 256, 256, 0, stream>>>(Kc, ypos, DIM, rt);
    attn_tile<<<attnGrid, 256, 0, stream>>>(Qc, DIM, Kc, DIM, Vc, DIM, bufAb, DIM);
    gemm_mfma<0, 0><<<64 * 6, 256, 0, stream>>>(bufAb, cpT, cross_proj_b, bufX,
                                                bufX, ROWS, 768, 768);

    // ---- MLP ----
    ln_bf16<<<ROWS, 256, 0, stream>>>(bufX, norm3_g, norm3_b, bufAb);
    gemm_mfma<1, 1><<<64 * 24, 256, 0, stream>>>(bufAb, fc1T, fc1_b, nullptr,
                                                 HID, ROWS, 3072, 768);
    gemm_mfma<0, 0><<<64 * 6, 256, 0, stream>>>(HID, fc2T, fc2_b, bufX,
                                                out, ROWS, 768, 3072);

    // ---- output y passthrough ----
    hipMemcpyAsync(out + SZ, y, SZ * sizeof(float), hipMemcpyDeviceToDevice, stream);
}

// Round 7
// 761.820 us; speedup vs baseline: 23.1441x; 1.6841x over previous
//
#include <hip/hip_runtime.h>
#include <hip/hip_bf16.h>
#include <math.h>

#define DIM 768
#define HEADS 12
#define HD 64
#define BB 8
#define NN 1024
#define EPSV 1e-5f

typedef unsigned int uint32;
typedef unsigned short ushort_t;
using short8 = __attribute__((ext_vector_type(8))) short;
using f32x4 = __attribute__((ext_vector_type(4))) float;

static __device__ inline ushort_t f2b(float v) {  // fp32 -> bf16 RNE
    uint32 u = __float_as_uint(v);
    return (ushort_t)((u + 0x7FFFu + ((u >> 16) & 1u)) >> 16);
}
static __device__ inline float b2f(ushort_t v) {
    return __uint_as_float((uint32)v << 16);
}

// ---------------- LayerNorm -> bf16: one block (256 thr) per row of 768 ---------
__global__ __launch_bounds__(256) void ln_bf16(const float* __restrict__ in,
                                               const float* __restrict__ g,
                                               const float* __restrict__ b,
                                               ushort_t* __restrict__ out) {
    int r = blockIdx.x;
    const float* x = in + (size_t)r * DIM;
    ushort_t* o = out + (size_t)r * DIM;
    int t = threadIdx.x;
    float v0 = x[t], v1 = x[t + 256], v2 = x[t + 512];
    float s = v0 + v1 + v2;
    float s2 = v0 * v0 + v1 * v1 + v2 * v2;
    for (int off = 32; off; off >>= 1) {
        s += __shfl_xor(s, off);
        s2 += __shfl_xor(s2, off);
    }
    __shared__ float ls[4], lq[4];
    int wid = t >> 6;
    if ((t & 63) == 0) { ls[wid] = s; lq[wid] = s2; }
    __syncthreads();
    s = ls[0] + ls[1] + ls[2] + ls[3];
    s2 = lq[0] + lq[1] + lq[2] + lq[3];
    float mean = s * (1.0f / DIM);
    float var = s2 * (1.0f / DIM) - mean * mean;
    float rs = rsqrtf(var + EPSV);
    o[t]       = f2b((v0 - mean) * rs * g[t]       + b[t]);
    o[t + 256] = f2b((v1 - mean) * rs * g[t + 256] + b[t + 256]);
    o[t + 512] = f2b((v2 - mean) * rs * g[t + 512] + b[t + 512]);
}

// ---------------- Weight cast+transpose: W[K][N] fp32 -> Wt[N][K] bf16 ----------
struct XArgs {
    const float* src[8];
    ushort_t* dst[8];
    int K[8], N[8];
    int tstart[9];
};
__global__ __launch_bounds__(256) void xform_w(XArgs a) {
    __shared__ float tl[32][33];
    int t = blockIdx.x;
    int w = 0;
    while (t >= a.tstart[w + 1]) w++;
    int lt = t - a.tstart[w];
    int ntn = a.N[w] >> 5;
    int k0 = (lt / ntn) * 32, n0 = (lt % ntn) * 32;
    const float* src = a.src[w];
    ushort_t* dst = a.dst[w];
    int K = a.K[w], N = a.N[w];
    int rr = threadIdx.x >> 5, cc = threadIdx.x & 31;
#pragma unroll
    for (int u = 0; u < 4; u++)
        tl[rr + u * 8][cc] = src[(size_t)(k0 + rr + u * 8) * N + n0 + cc];
    __syncthreads();
#pragma unroll
    for (int u = 0; u < 4; u++)
        dst[(size_t)(n0 + rr + u * 8) * K + k0 + cc] = f2b(tl[cc][rr + u * 8]);
}

// ---------------- bf16 MFMA GEMM: C[M,N] = A[M,K] @ Wt[N,K]^T (+bias/gelu/res) --
template <int ACT, int OBF16>
__global__ __launch_bounds__(256) void gemm_mfma(const ushort_t* __restrict__ A,
                                                 const ushort_t* __restrict__ Wt,
                                                 const float* __restrict__ bias,
                                                 const float* res,
                                                 void* Cout, int M, int N, int K) {
    __shared__ ushort_t As[128][40];
    __shared__ ushort_t Bs[128][40];
    int nblk = N >> 7;
    int bx = blockIdx.x % nblk, by = blockIdx.x / nblk;
    int m0 = by * 128, n0 = bx * 128;
    int tid = threadIdx.x;
    int wid = tid >> 6, lane = tid & 63;
    int wm = wid >> 1, wn = wid & 1;
    int srow = tid >> 2, skoff = (tid & 3) * 8;

    const ushort_t* Abase = A + (size_t)m0 * K;
    const ushort_t* Bbase = Wt + (size_t)n0 * K;

    f32x4 acc[4][4] = {};
    for (int k0 = 0; k0 < K; k0 += 32) {
        __syncthreads();
        *(uint4*)&As[srow][skoff]      = *(const uint4*)(Abase + (size_t)srow * K + k0 + skoff);
        *(uint4*)&As[srow + 64][skoff] = *(const uint4*)(Abase + (size_t)(srow + 64) * K + k0 + skoff);
        *(uint4*)&Bs[srow][skoff]      = *(const uint4*)(Bbase + (size_t)srow * K + k0 + skoff);
        *(uint4*)&Bs[srow + 64][skoff] = *(const uint4*)(Bbase + (size_t)(srow + 64) * K + k0 + skoff);
        __syncthreads();
        int c16 = lane & 15, k8 = (lane >> 4) * 8;
        short8 af[4], bfr[4];
#pragma unroll
        for (int i = 0; i < 4; i++) {
            af[i]  = *(const short8*)&As[wm * 64 + i * 16 + c16][k8];
            bfr[i] = *(const short8*)&Bs[wn * 64 + i * 16 + c16][k8];
        }
#pragma unroll
        for (int i = 0; i < 4; i++)
#pragma unroll
            for (int j = 0; j < 4; j++)
                acc[i][j] = __builtin_amdgcn_mfma_f32_16x16x32_bf16(af[i], bfr[j],
                                                                    acc[i][j], 0, 0, 0);
    }

    int col = lane & 15, rg = (lane >> 4) * 4;
#pragma unroll
    for (int j = 0; j < 4; j++) {
        int n = n0 + wn * 64 + j * 16 + col;
        float bv = bias ? bias[n] : 0.0f;
#pragma unroll
        for (int i = 0; i < 4; i++) {
#pragma unroll
            for (int r = 0; r < 4; r++) {
                int m = m0 + wm * 64 + i * 16 + rg + r;
                float v = acc[i][j][r] + bv;
                if (ACT == 1) v = 0.5f * v * (1.0f + erff(v * 0.70710678118654752f));
                if (res) v += res[(size_t)m * N + n];
                if (OBF16) ((ushort_t*)Cout)[(size_t)m * N + n] = f2b(v);
                else       ((float*)Cout)[(size_t)m * N + n] = v;
            }
        }
    }
}

// ---------------- RoPE2D in place on bf16 [B*N, rowStride] ----------------------
__global__ __launch_bounds__(256) void rope_bf16(ushort_t* __restrict__ t,
                                                 const int* __restrict__ pos,
                                                 int rowStride, int total) {
    int idx = blockIdx.x * blockDim.x + threadIdx.x;
    if (idx >= total) return;
    int i = idx & 15;
    int half = (idx >> 4) & 1;
    int h = (idx >> 5) % HEADS;
    int bn = idx / (HEADS * 32);
    int p = pos[(size_t)bn * 2 + half];
    float inv = powf(100.0f, -(float)i / 16.0f);
    float f = (float)p * inv;
    float c, s;
    sincosf(f, &s, &c);
    ushort_t* base = t + (size_t)bn * rowStride + h * HD + half * 32;
    float t1 = b2f(base[i]), t2 = b2f(base[i + 16]);
    base[i]      = f2b(t1 * c - t2 * s);
    base[i + 16] = f2b(t2 * c + t1 * s);
}

// ---------------- MFMA flash attention (bf16 in/out) ----------------------------
// grid = BB*HEADS*(NN/64); 256 thr = 4 waves; wave w owns Q-rows w*16..w*16+15.
__global__ __launch_bounds__(256) void attn_mfma(const ushort_t* __restrict__ Q, int sq,
                                                 const ushort_t* __restrict__ K, int sk,
                                                 const ushort_t* __restrict__ V, int sv,
                                                 ushort_t* __restrict__ O, int so) {
    __shared__ ushort_t Qs[64][72];   // [q][d]
    __shared__ ushort_t Ks[64][72];   // [key][d]
    __shared__ ushort_t Vt[64][72];   // [d][key]  (transposed during staging)
    __shared__ ushort_t Ps[64][72];   // [q][key]  (wave-private 16-row strips)

    int bid = blockIdx.x;
    int qb = bid & 15;
    int h = (bid >> 4) % HEADS;
    int b = bid / (16 * HEADS);
    int n0 = qb * 64;

    int tid = threadIdx.x;
    int lane = tid & 63, wq = tid >> 6;
    int l15 = lane & 15, lh = lane >> 4;

    const ushort_t* Qbase = Q + (size_t)b * NN * sq + h * HD;
    const ushort_t* Kbase = K + (size_t)b * NN * sk + h * HD;
    const ushort_t* Vbase = V + (size_t)b * NN * sv + h * HD;
    ushort_t* Obase = O + (size_t)b * NN * so + h * HD;

    {   // stage Q tile: thread t -> row t>>2, cols (t&3)*16 .. +15
        int row = tid >> 2, c0 = (tid & 3) * 16;
        const ushort_t* src = Qbase + (size_t)(n0 + row) * sq + c0;
        *(uint4*)&Qs[row][c0]     = *(const uint4*)src;
        *(uint4*)&Qs[row][c0 + 8] = *(const uint4*)(src + 8);
    }

    f32x4 oacc[4] = {};
    float mrow[4] = {-1e30f, -1e30f, -1e30f, -1e30f};
    float lrow[4] = {};

    for (int kt = 0; kt < NN / 64; kt++) {
        __syncthreads();  // prev tile's reads of Ks/Vt done (and Qs staged, iter 0)
        {
            int row = tid >> 2, c0 = (tid & 3) * 16;
            const ushort_t* ks = Kbase + (size_t)(kt * 64 + row) * sk + c0;
            *(uint4*)&Ks[row][c0]     = *(const uint4*)ks;
            *(uint4*)&Ks[row][c0 + 8] = *(const uint4*)(ks + 8);
            const ushort_t* vs = Vbase + (size_t)(kt * 64 + row) * sv + c0;
            uint4 v0 = *(const uint4*)vs;
            uint4 v1 = *(const uint4*)(vs + 8);
            const ushort_t* pv = (const ushort_t*)&v0;
#pragma unroll
            for (int u = 0; u < 8; u++) Vt[c0 + u][row] = pv[u];
            pv = (const ushort_t*)&v1;
#pragma unroll
            for (int u = 0; u < 8; u++) Vt[c0 + 8 + u][row] = pv[u];
        }
        __syncthreads();

        // S = Q K^T  (per wave: 16 q-rows x 64 keys)
        f32x4 s[4] = {};
#pragma unroll
        for (int ks8 = 0; ks8 < 2; ks8++) {
            short8 aq = *(const short8*)&Qs[wq * 16 + l15][ks8 * 32 + lh * 8];
#pragma unroll
            for (int j = 0; j < 4; j++) {
                short8 bk = *(const short8*)&Ks[j * 16 + l15][ks8 * 32 + lh * 8];
                s[j] = __builtin_amdgcn_mfma_f32_16x16x32_bf16(aq, bk, s[j], 0, 0, 0);
            }
        }

        // online softmax; lane owns rows (lh*4 + r), col l15 of each 16-col frag
        float corr[4];
#pragma unroll
        for (int r = 0; r < 4; r++) {
            float v0 = s[0][r] * 0.125f, v1 = s[1][r] * 0.125f;
            float v2 = s[2][r] * 0.125f, v3 = s[3][r] * 0.125f;
            float rm = fmaxf(fmaxf(v0, v1), fmaxf(v2, v3));
            rm = fmaxf(rm, __shfl_xor(rm, 1));
            rm = fmaxf(rm, __shfl_xor(rm, 2));
            rm = fmaxf(rm, __shfl_xor(rm, 4));
            rm = fmaxf(rm, __shfl_xor(rm, 8));
            float mn = fmaxf(mrow[r], rm);
            corr[r] = __expf(mrow[r] - mn);
            mrow[r] = mn;
            float p0 = __expf(v0 - mn), p1 = __expf(v1 - mn);
            float p2 = __expf(v2 - mn), p3 = __expf(v3 - mn);
            float ps = p0 + p1 + p2 + p3;
            ps += __shfl_xor(ps, 1);
            ps += __shfl_xor(ps, 2);
            ps += __shfl_xor(ps, 4);
            ps += __shfl_xor(ps, 8);
            lrow[r] = lrow[r] * corr[r] + ps;
            int qrow = wq * 16 + lh * 4 + r;
            Ps[qrow][0 * 16 + l15] = f2b(p0);
            Ps[qrow][1 * 16 + l15] = f2b(p1);
            Ps[qrow][2 * 16 + l15] = f2b(p2);
            Ps[qrow][3 * 16 + l15] = f2b(p3);
        }
#pragma unroll
        for (int j = 0; j < 4; j++)
#pragma unroll
            for (int r = 0; r < 4; r++) oacc[j][r] *= corr[r];

        // O += P @ V   (A-frag from own wave's Ps strip -> no barrier needed)
#pragma unroll
        for (int ks8 = 0; ks8 < 2; ks8++) {
            short8 ap = *(const short8*)&Ps[wq * 16 + l15][ks8 * 32 + lh * 8];
#pragma unroll
            for (int j = 0; j < 4; j++) {
                short8 bv = *(const short8*)&Vt[j * 16 + l15][ks8 * 32 + lh * 8];
                oacc[j] = __builtin_amdgcn_mfma_f32_16x16x32_bf16(ap, bv, oacc[j], 0, 0, 0);
            }
        }
    }

    // epilogue: normalize, write bf16
#pragma unroll
    for (int r = 0; r < 4; r++) {
        float inv = 1.0f / lrow[r];
        int qrow = n0 + wq * 16 + lh * 4 + r;
#pragma unroll
        for (int j = 0; j < 4; j++)
            Obase[(size_t)qrow * so + j * 16 + l15] = f2b(oacc[j][r] * inv);
    }
}

// ---------------- sentinel fill -------------------------------------------------
__global__ __launch_bounds__(256) void fill_f32(float* __restrict__ out, float v, int n) {
    int i = blockIdx.x * 256 + threadIdx.x;
    if (i < n) out[i] = v;
}

extern "C" void kernel_launch(void* const* d_in, const int* in_sizes, int n_in,
                              void* d_out, int out_size, void* d_ws, size_t ws_size,
                              hipStream_t stream) {
    const float* x = (const float*)d_in[0];
    const float* y = (const float*)d_in[1];
    const int* xpos = (const int*)d_in[2];
    const int* ypos = (const int*)d_in[3];
    const float* norm1_g = (const float*)d_in[4];
    const float* norm1_b = (const float*)d_in[5];
    const float* norm2_g = (const float*)d_in[6];
    const float* norm2_b = (const float*)d_in[7];
    const float* norm3_g = (const float*)d_in[8];
    const float* norm3_b = (const float*)d_in[9];
    const float* normy_g = (const float*)d_in[10];
    const float* normy_b = (const float*)d_in[11];
    const float* qkv_w = (const float*)d_in[12];
    const float* attn_proj_w = (const float*)d_in[13];
    const float* attn_proj_b = (const float*)d_in[14];
    const float* projq_w = (const float*)d_in[15];
    const float* projk_w = (const float*)d_in[16];
    const float* projv_w = (const float*)d_in[17];
    const float* cross_proj_w = (const float*)d_in[18];
    const float* cross_proj_b = (const float*)d_in[19];
    const float* fc1_w = (const float*)d_in[20];
    const float* fc1_b = (const float*)d_in[21];
    const float* fc2_w = (const float*)d_in[22];
    const float* fc2_b = (const float*)d_in[23];
    float* out = (float*)d_out;

    const size_t SZ = (size_t)BB * NN * DIM;  // 6291456
    const int ROWS = BB * NN;                 // 8192

    // ws layout: bufX f32(SZ) | bufAb bf16(SZ) | bufQKVb bf16(4*SZ) | wts bf16
    const size_t WS_NEED = SZ * 4 + SZ * 2 + 4 * SZ * 2 + 9437184ull * 2;  // ~107 MB

    {   // ---- interface sentinels ----
        const int expect[24] = {
            (int)SZ, (int)SZ, BB * NN * 2, BB * NN * 2,
            DIM, DIM, DIM, DIM, DIM, DIM, DIM, DIM,
            DIM * 3 * DIM, DIM * DIM, DIM,
            DIM * DIM, DIM * DIM, DIM * DIM, DIM * DIM, DIM,
            DIM * 4 * DIM, 4 * DIM, 4 * DIM * DIM, DIM};
        float sentinel = 0.0f;
        if (n_in != 24) sentinel = 2000.0f;
        else {
            for (int i = 0; i < 24; i++)
                if (in_sizes[i] != expect[i]) { sentinel = 1000.0f + i; break; }
        }
        if (sentinel == 0.0f && ws_size < WS_NEED) sentinel = 3000.0f;
        if (sentinel == 0.0f && out_size != (int)(2 * SZ)) sentinel = 4000.0f;
        if (sentinel != 0.0f) {
            fill_f32<<<(int)((SZ + 255) / 256), 256, 0, stream>>>(out, sentinel, (int)SZ);
            return;
        }
    }

    float* bufX = (float*)d_ws;
    ushort_t* bufAb = (ushort_t*)(bufX + SZ);        // SZ bf16
    ushort_t* bufQKVb = bufAb + SZ;                  // 4*SZ bf16 (QKV / cross / HID)
    ushort_t* wts = bufQKVb + 4 * SZ;

    ushort_t* qkvT = wts;                            // [2304][768]
    ushort_t* apT  = qkvT + 2304 * 768;
    ushort_t* pqT  = apT + 768 * 768;
    ushort_t* pkT  = pqT + 768 * 768;
    ushort_t* pvT  = pkT + 768 * 768;
    ushort_t* cpT  = pvT + 768 * 768;
    ushort_t* fc1T = cpT + 768 * 768;                // [3072][768]
    ushort_t* fc2T = fc1T + 3072 * 768;              // [768][3072]
    ushort_t* HID  = bufQKVb;                        // [8192][3072] bf16 (MLP phase)

    // ---- one-time weight cast+transpose ----
    XArgs xa;
    xa.src[0] = qkv_w;        xa.dst[0] = qkvT; xa.K[0] = 768;  xa.N[0] = 2304;
    xa.src[1] = attn_proj_w;  xa.dst[1] = apT;  xa.K[1] = 768;  xa.N[1] = 768;
    xa.src[2] = projq_w;      xa.dst[2] = pqT;  xa.K[2] = 768;  xa.N[2] = 768;
    xa.src[3] = projk_w;      xa.dst[3] = pkT;  xa.K[3] = 768;  xa.N[3] = 768;
    xa.src[4] = projv_w;      xa.dst[4] = pvT;  xa.K[4] = 768;  xa.N[4] = 768;
    xa.src[5] = cross_proj_w; xa.dst[5] = cpT;  xa.K[5] = 768;  xa.N[5] = 768;
    xa.src[6] = fc1_w;        xa.dst[6] = fc1T; xa.K[6] = 768;  xa.N[6] = 3072;
    xa.src[7] = fc2_w;        xa.dst[7] = fc2T; xa.K[7] = 3072; xa.N[7] = 768;
    int acc_t = 0;
    for (int i = 0; i < 8; i++) {
        xa.tstart[i] = acc_t;
        acc_t += (xa.K[i] / 32) * (xa.N[i] / 32);
    }
    xa.tstart[8] = acc_t;  // 9216
    xform_w<<<acc_t, 256, 0, stream>>>(xa);

    const int rt = ROWS * HEADS * 32;               // 3145728
    const int attnGrid = BB * HEADS * (NN / 64);    // 1536

    // ---- self attention ----
    ln_bf16<<<ROWS, 256, 0, stream>>>(x, norm1_g, norm1_b, bufAb);
    gemm_mfma<0, 1><<<64 * 18, 256, 0, stream>>>(bufAb, qkvT, nullptr, nullptr,
                                                 bufQKVb, ROWS, 2304, 768);
    rope_bf16<<<rt / 256, 256, 0, stream>>>(bufQKVb, xpos, 2304, rt);
    rope_bf16<<<rt / 256, 256, 0, stream>>>(bufQKVb + DIM, xpos, 2304, rt);
    attn_mfma<<<attnGrid, 256, 0, stream>>>(bufQKVb, 2304, bufQKVb + DIM, 2304,
                                            bufQKVb + 2 * DIM, 2304, bufAb, DIM);
    gemm_mfma<0, 0><<<64 * 6, 256, 0, stream>>>(bufAb, apT, attn_proj_b, x,
                                                bufX, ROWS, 768, 768);

    // ---- cross attention ----
    ushort_t* Qc = bufQKVb;
    ushort_t* Kc = bufQKVb + SZ;
    ushort_t* Vc = bufQKVb + 2 * SZ;
    ln_bf16<<<ROWS, 256, 0, stream>>>(bufX, norm2_g, norm2_b, bufAb);
    gemm_mfma<0, 1><<<64 * 6, 256, 0, stream>>>(bufAb, pqT, nullptr, nullptr,
                                                Qc, ROWS, 768, 768);
    ln_bf16<<<ROWS, 256, 0, stream>>>(y, normy_g, normy_b, bufAb);
    gemm_mfma<0, 1><<<64 * 6, 256, 0, stream>>>(bufAb, pkT, nullptr, nullptr,
                                                Kc, ROWS, 768, 768);
    gemm_mfma<0, 1><<<64 * 6, 256, 0, stream>>>(bufAb, pvT, nullptr, nullptr,
                                                Vc, ROWS, 768, 768);
    rope_bf16<<<rt / 256, 256, 0, stream>>>(Qc, xpos, DIM, rt);
    rope_bf16<<<rt / 256, 256, 0, stream>>>(Kc, ypos, DIM, rt);
    attn_mfma<<<attnGrid, 256, 0, stream>>>(Qc, DIM, Kc, DIM, Vc, DIM, bufAb, DIM);
    gemm_mfma<0, 0><<<64 * 6, 256, 0, stream>>>(bufAb, cpT, cross_proj_b, bufX,
                                                bufX, ROWS, 768, 768);

    // ---- MLP ----
    ln_bf16<<<ROWS, 256, 0, stream>>>(bufX, norm3_g, norm3_b, bufAb);
    gemm_mfma<1, 1><<<64 * 24, 256, 0, stream>>>(bufAb, fc1T, fc1_b, nullptr,
                                                 HID, ROWS, 3072, 768);
    gemm_mfma<0, 0><<<64 * 6, 256, 0, stream>>>(HID, fc2T, fc2_b, bufX,
                                                out, ROWS, 768, 3072);

    // ---- output y passthrough ----
    hipMemcpyAsync(out + SZ, y, SZ * sizeof(float), hipMemcpyDeviceToDevice, stream);
}

// Round 8
// 647.074 us; speedup vs baseline: 27.2483x; 1.1773x over previous
//
#include <hip/hip_runtime.h>
#include <hip/hip_bf16.h>
#include <math.h>

#define DIM 768
#define HEADS 12
#define HD 64
#define BB 8
#define NN 1024
#define EPSV 1e-5f

typedef unsigned int uint32;
typedef unsigned short ushort_t;
using short8 = __attribute__((ext_vector_type(8))) short;
using f32x4 = __attribute__((ext_vector_type(4))) float;

static __device__ inline ushort_t f2b(float v) {  // fp32 -> bf16 RNE
    uint32 u = __float_as_uint(v);
    return (ushort_t)((u + 0x7FFFu + ((u >> 16) & 1u)) >> 16);
}
static __device__ inline float b2f(ushort_t v) {
    return __uint_as_float((uint32)v << 16);
}

// ---------------- LayerNorm -> bf16: one block (256 thr) per row of 768 ---------
__global__ __launch_bounds__(256) void ln_bf16(const float* __restrict__ in,
                                               const float* __restrict__ g,
                                               const float* __restrict__ b,
                                               ushort_t* __restrict__ out) {
    int r = blockIdx.x;
    const float* x = in + (size_t)r * DIM;
    ushort_t* o = out + (size_t)r * DIM;
    int t = threadIdx.x;
    float v0 = x[t], v1 = x[t + 256], v2 = x[t + 512];
    float s = v0 + v1 + v2;
    float s2 = v0 * v0 + v1 * v1 + v2 * v2;
    for (int off = 32; off; off >>= 1) {
        s += __shfl_xor(s, off);
        s2 += __shfl_xor(s2, off);
    }
    __shared__ float ls[4], lq[4];
    int wid = t >> 6;
    if ((t & 63) == 0) { ls[wid] = s; lq[wid] = s2; }
    __syncthreads();
    s = ls[0] + ls[1] + ls[2] + ls[3];
    s2 = lq[0] + lq[1] + lq[2] + lq[3];
    float mean = s * (1.0f / DIM);
    float var = s2 * (1.0f / DIM) - mean * mean;
    float rs = rsqrtf(var + EPSV);
    o[t]       = f2b((v0 - mean) * rs * g[t]       + b[t]);
    o[t + 256] = f2b((v1 - mean) * rs * g[t + 256] + b[t + 256]);
    o[t + 512] = f2b((v2 - mean) * rs * g[t + 512] + b[t + 512]);
}

// ---------------- Weight cast+transpose: W[K][N] fp32 -> Wt[N][K] bf16 ----------
struct XArgs {
    const float* src[8];
    ushort_t* dst[8];
    int K[8], N[8];
    int tstart[9];
};
__global__ __launch_bounds__(256) void xform_w(XArgs a) {
    __shared__ float tl[32][33];
    int t = blockIdx.x;
    int w = 0;
    while (t >= a.tstart[w + 1]) w++;
    int lt = t - a.tstart[w];
    int ntn = a.N[w] >> 5;
    int k0 = (lt / ntn) * 32, n0 = (lt % ntn) * 32;
    const float* src = a.src[w];
    ushort_t* dst = a.dst[w];
    int K = a.K[w], N = a.N[w];
    int rr = threadIdx.x >> 5, cc = threadIdx.x & 31;
#pragma unroll
    for (int u = 0; u < 4; u++)
        tl[rr + u * 8][cc] = src[(size_t)(k0 + rr + u * 8) * N + n0 + cc];
    __syncthreads();
#pragma unroll
    for (int u = 0; u < 4; u++)
        dst[(size_t)(n0 + rr + u * 8) * K + k0 + cc] = f2b(tl[cc][rr + u * 8]);
}

// ---------------- bf16 MFMA GEMM, register-prefetch pipeline --------------------
// C[M,N] = A[M,K] @ Wt[N,K]^T (+bias)(+gelu)(+res). 128x128 tile, 4 waves (2x2).
template <int ACT, int OBF16>
__global__ __launch_bounds__(256) void gemm_mfma(const ushort_t* __restrict__ A,
                                                 const ushort_t* __restrict__ Wt,
                                                 const float* __restrict__ bias,
                                                 const float* res,
                                                 void* Cout, int M, int N, int K) {
    __shared__ ushort_t As[128][40];
    __shared__ ushort_t Bs[128][40];
    int nblk = N >> 7;
    int bx = blockIdx.x % nblk, by = blockIdx.x / nblk;
    int m0 = by * 128, n0 = bx * 128;
    int tid = threadIdx.x;
    int wid = tid >> 6, lane = tid & 63;
    int wm = wid >> 1, wn = wid & 1;
    int srow = tid >> 2, skoff = (tid & 3) * 8;

    const ushort_t* pa0 = A + (size_t)(m0 + srow) * K + skoff;
    const ushort_t* pa1 = pa0 + (size_t)64 * K;
    const ushort_t* pb0 = Wt + (size_t)(n0 + srow) * K + skoff;
    const ushort_t* pb1 = pb0 + (size_t)64 * K;

    uint4 ra0 = *(const uint4*)pa0;
    uint4 ra1 = *(const uint4*)pa1;
    uint4 rb0 = *(const uint4*)pb0;
    uint4 rb1 = *(const uint4*)pb1;

    f32x4 acc[4][4] = {};
    for (int k0 = 0; k0 < K; k0 += 32) {
        __syncthreads();                       // prev iter frag reads done
        *(uint4*)&As[srow][skoff] = ra0;
        *(uint4*)&As[srow + 64][skoff] = ra1;
        *(uint4*)&Bs[srow][skoff] = rb0;
        *(uint4*)&Bs[srow + 64][skoff] = rb1;
        __syncthreads();
        if (k0 + 32 < K) {                     // prefetch next K-step (hidden by MFMA)
            ra0 = *(const uint4*)(pa0 + k0 + 32);
            ra1 = *(const uint4*)(pa1 + k0 + 32);
            rb0 = *(const uint4*)(pb0 + k0 + 32);
            rb1 = *(const uint4*)(pb1 + k0 + 32);
        }
        int c16 = lane & 15, k8 = (lane >> 4) * 8;
        short8 af[4], bfr[4];
#pragma unroll
        for (int i = 0; i < 4; i++) {
            af[i]  = *(const short8*)&As[wm * 64 + i * 16 + c16][k8];
            bfr[i] = *(const short8*)&Bs[wn * 64 + i * 16 + c16][k8];
        }
#pragma unroll
        for (int i = 0; i < 4; i++)
#pragma unroll
            for (int j = 0; j < 4; j++)
                acc[i][j] = __builtin_amdgcn_mfma_f32_16x16x32_bf16(af[i], bfr[j],
                                                                    acc[i][j], 0, 0, 0);
    }

    int col = lane & 15, rg = (lane >> 4) * 4;
#pragma unroll
    for (int j = 0; j < 4; j++) {
        int n = n0 + wn * 64 + j * 16 + col;
        float bv = bias ? bias[n] : 0.0f;
#pragma unroll
        for (int i = 0; i < 4; i++) {
#pragma unroll
            for (int r = 0; r < 4; r++) {
                int m = m0 + wm * 64 + i * 16 + rg + r;
                float v = acc[i][j][r] + bv;
                if (ACT == 1) v = 0.5f * v * (1.0f + erff(v * 0.70710678118654752f));
                if (res) v += res[(size_t)m * N + n];
                if (OBF16) ((ushort_t*)Cout)[(size_t)m * N + n] = f2b(v);
                else       ((float*)Cout)[(size_t)m * N + n] = v;
            }
        }
    }
}

// ---------------- RoPE2D x2 streams, in place on bf16 ---------------------------
__global__ __launch_bounds__(256) void rope2_bf16(ushort_t* __restrict__ ta,
                                                  const int* __restrict__ pa, int sa,
                                                  ushort_t* __restrict__ tb,
                                                  const int* __restrict__ pb, int sb,
                                                  int rt) {
    int idx = blockIdx.x * 256 + threadIdx.x;
    ushort_t* t;
    const int* pos;
    int rowStride;
    if (idx >= rt) { idx -= rt; t = tb; pos = pb; rowStride = sb; }
    else           { t = ta; pos = pa; rowStride = sa; }
    int i = idx & 15;
    int half = (idx >> 4) & 1;
    int h = (idx >> 5) % HEADS;
    int bn = idx / (HEADS * 32);
    int p = pos[(size_t)bn * 2 + half];
    float inv = powf(100.0f, -(float)i / 16.0f);
    float f = (float)p * inv;
    float c, s;
    sincosf(f, &s, &c);
    ushort_t* base = t + (size_t)bn * rowStride + h * HD + half * 32;
    float t1 = b2f(base[i]), t2 = b2f(base[i + 16]);
    base[i]      = f2b(t1 * c - t2 * s);
    base[i + 16] = f2b(t2 * c + t1 * s);
}

// ---------------- V global transpose: [b][n][h*64+d] -> VT[b][h][d][n] ----------
__global__ __launch_bounds__(256) void transpose_v(const ushort_t* __restrict__ src,
                                                   int ss, ushort_t* __restrict__ dst) {
    __shared__ ushort_t tl[64][66];
    int bid = blockIdx.x;       // b*HEADS*16 + h*16 + nt
    int nt = bid & 15;
    int h = (bid >> 4) % HEADS;
    int b = bid / (16 * HEADS);
    int n0 = nt * 64;
    int t = threadIdx.x;
    int r = t >> 2, c0 = (t & 3) * 16;
    const ushort_t* s = src + ((size_t)(b * NN) + n0 + r) * ss + h * HD + c0;
    *(uint4*)&tl[r][c0]     = *(const uint4*)s;
    *(uint4*)&tl[r][c0 + 8] = *(const uint4*)(s + 8);
    __syncthreads();
    ushort_t* d = dst + (((size_t)(b * HEADS + h)) * HD + r) * NN + n0 + c0;
    ushort_t tmp[16];
#pragma unroll
    for (int u = 0; u < 16; u++) tmp[u] = tl[c0 + u][r];
    *(uint4*)d       = *(uint4*)tmp;
    *(uint4*)(d + 8) = *(uint4*)(tmp + 8);
}

// ---------------- MFMA flash attention (bf16), V^T input, K/V prefetch ----------
// grid = BB*HEADS*(NN/64); 256 thr = 4 waves; wave w owns Q-rows w*16..w*16+15.
__global__ __launch_bounds__(256) void attn_mfma(const ushort_t* __restrict__ Q, int sq,
                                                 const ushort_t* __restrict__ K, int sk,
                                                 const ushort_t* __restrict__ VT,
                                                 ushort_t* __restrict__ O, int so) {
    __shared__ ushort_t Qs[64][72];   // [q][d]
    __shared__ ushort_t Ks[64][72];   // [key][d]
    __shared__ ushort_t Vs[64][72];   // [d][key]
    __shared__ ushort_t Ps[64][72];   // [q][key]  (wave-private strips)

    int bid = blockIdx.x;
    int qb = bid & 15;
    int h = (bid >> 4) % HEADS;
    int b = bid / (16 * HEADS);
    int n0 = qb * 64;

    int tid = threadIdx.x;
    int lane = tid & 63, wq = tid >> 6;
    int l15 = lane & 15, lh = lane >> 4;

    const ushort_t* Qbase = Q + (size_t)b * NN * sq + h * HD;
    const ushort_t* Kbase = K + (size_t)b * NN * sk + h * HD;
    const ushort_t* VTbase = VT + ((size_t)(b * HEADS + h)) * HD * NN;  // [d][n]
    ushort_t* Obase = O + (size_t)b * NN * so + h * HD;

    int row = tid >> 2, c0 = (tid & 3) * 16;
    {   // stage Q tile
        const ushort_t* src = Qbase + (size_t)(n0 + row) * sq + c0;
        *(uint4*)&Qs[row][c0]     = *(const uint4*)src;
        *(uint4*)&Qs[row][c0 + 8] = *(const uint4*)(src + 8);
    }

    const ushort_t* kp = Kbase + (size_t)row * sk + c0;   // + kt*64*sk per tile
    const ushort_t* vp = VTbase + (size_t)row * NN + c0;  // + kt*64 per tile
    uint4 rk0 = *(const uint4*)kp, rk1 = *(const uint4*)(kp + 8);
    uint4 rv0 = *(const uint4*)vp, rv1 = *(const uint4*)(vp + 8);

    f32x4 oacc[4] = {};
    float mrow[4] = {-1e30f, -1e30f, -1e30f, -1e30f};
    float lrow[4] = {};

    for (int kt = 0; kt < NN / 64; kt++) {
        __syncthreads();  // prev tile reads done (and Qs staged, iter 0)
        *(uint4*)&Ks[row][c0]     = rk0;
        *(uint4*)&Ks[row][c0 + 8] = rk1;
        *(uint4*)&Vs[row][c0]     = rv0;
        *(uint4*)&Vs[row][c0 + 8] = rv1;
        __syncthreads();
        if (kt + 1 < NN / 64) {   // prefetch next K/V tile (hidden by compute)
            const ushort_t* kp2 = kp + (size_t)(kt + 1) * 64 * sk;
            const ushort_t* vp2 = vp + (size_t)(kt + 1) * 64;
            rk0 = *(const uint4*)kp2;
            rk1 = *(const uint4*)(kp2 + 8);
            rv0 = *(const uint4*)vp2;
            rv1 = *(const uint4*)(vp2 + 8);
        }

        // S = Q K^T  (per wave: 16 q-rows x 64 keys)
        f32x4 s[4] = {};
#pragma unroll
        for (int ks8 = 0; ks8 < 2; ks8++) {
            short8 aq = *(const short8*)&Qs[wq * 16 + l15][ks8 * 32 + lh * 8];
#pragma unroll
            for (int j = 0; j < 4; j++) {
                short8 bk = *(const short8*)&Ks[j * 16 + l15][ks8 * 32 + lh * 8];
                s[j] = __builtin_amdgcn_mfma_f32_16x16x32_bf16(aq, bk, s[j], 0, 0, 0);
            }
        }

        // online softmax; lane owns rows (lh*4 + r), col l15 of each 16-col frag
        float corr[4];
#pragma unroll
        for (int r = 0; r < 4; r++) {
            float v0 = s[0][r] * 0.125f, v1 = s[1][r] * 0.125f;
            float v2 = s[2][r] * 0.125f, v3 = s[3][r] * 0.125f;
            float rm = fmaxf(fmaxf(v0, v1), fmaxf(v2, v3));
            rm = fmaxf(rm, __shfl_xor(rm, 1));
            rm = fmaxf(rm, __shfl_xor(rm, 2));
            rm = fmaxf(rm, __shfl_xor(rm, 4));
            rm = fmaxf(rm, __shfl_xor(rm, 8));
            float mn = fmaxf(mrow[r], rm);
            corr[r] = __expf(mrow[r] - mn);
            mrow[r] = mn;
            float p0 = __expf(v0 - mn), p1 = __expf(v1 - mn);
            float p2 = __expf(v2 - mn), p3 = __expf(v3 - mn);
            float ps = p0 + p1 + p2 + p3;
            ps += __shfl_xor(ps, 1);
            ps += __shfl_xor(ps, 2);
            ps += __shfl_xor(ps, 4);
            ps += __shfl_xor(ps, 8);
            lrow[r] = lrow[r] * corr[r] + ps;
            int qrow = wq * 16 + lh * 4 + r;
            Ps[qrow][0 * 16 + l15] = f2b(p0);
            Ps[qrow][1 * 16 + l15] = f2b(p1);
            Ps[qrow][2 * 16 + l15] = f2b(p2);
            Ps[qrow][3 * 16 + l15] = f2b(p3);
        }
#pragma unroll
        for (int j = 0; j < 4; j++)
#pragma unroll
            for (int r = 0; r < 4; r++) oacc[j][r] *= corr[r];

        // O += P @ V   (A-frag from own wave's Ps strip; B-frag natural Vs[d][key])
#pragma unroll
        for (int ks8 = 0; ks8 < 2; ks8++) {
            short8 ap = *(const short8*)&Ps[wq * 16 + l15][ks8 * 32 + lh * 8];
#pragma unroll
            for (int j = 0; j < 4; j++) {
                short8 bv = *(const short8*)&Vs[j * 16 + l15][ks8 * 32 + lh * 8];
                oacc[j] = __builtin_amdgcn_mfma_f32_16x16x32_bf16(ap, bv, oacc[j], 0, 0, 0);
            }
        }
    }

    // epilogue: normalize, write bf16
#pragma unroll
    for (int r = 0; r < 4; r++) {
        float inv = 1.0f / lrow[r];
        int qrow = n0 + wq * 16 + lh * 4 + r;
#pragma unroll
        for (int j = 0; j < 4; j++)
            Obase[(size_t)qrow * so + j * 16 + l15] = f2b(oacc[j][r] * inv);
    }
}

// ---------------- sentinel fill -------------------------------------------------
__global__ __launch_bounds__(256) void fill_f32(float* __restrict__ out, float v, int n) {
    int i = blockIdx.x * 256 + threadIdx.x;
    if (i < n) out[i] = v;
}

extern "C" void kernel_launch(void* const* d_in, const int* in_sizes, int n_in,
                              void* d_out, int out_size, void* d_ws, size_t ws_size,
                              hipStream_t stream) {
    const float* x = (const float*)d_in[0];
    const float* y = (const float*)d_in[1];
    const int* xpos = (const int*)d_in[2];
    const int* ypos = (const int*)d_in[3];
    const float* norm1_g = (const float*)d_in[4];
    const float* norm1_b = (const float*)d_in[5];
    const float* norm2_g = (const float*)d_in[6];
    const float* norm2_b = (const float*)d_in[7];
    const float* norm3_g = (const float*)d_in[8];
    const float* norm3_b = (const float*)d_in[9];
    const float* normy_g = (const float*)d_in[10];
    const float* normy_b = (const float*)d_in[11];
    const float* qkv_w = (const float*)d_in[12];
    const float* attn_proj_w = (const float*)d_in[13];
    const float* attn_proj_b = (const float*)d_in[14];
    const float* projq_w = (const float*)d_in[15];
    const float* projk_w = (const float*)d_in[16];
    const float* projv_w = (const float*)d_in[17];
    const float* cross_proj_w = (const float*)d_in[18];
    const float* cross_proj_b = (const float*)d_in[19];
    const float* fc1_w = (const float*)d_in[20];
    const float* fc1_b = (const float*)d_in[21];
    const float* fc2_w = (const float*)d_in[22];
    const float* fc2_b = (const float*)d_in[23];
    float* out = (float*)d_out;

    const size_t SZ = (size_t)BB * NN * DIM;  // 6291456
    const int ROWS = BB * NN;                 // 8192

    const size_t WS_NEED = SZ * 4 + SZ * 2 + 4 * SZ * 2 + 9437184ull * 2;  // ~107 MB

    {   // ---- interface sentinels ----
        const int expect[24] = {
            (int)SZ, (int)SZ, BB * NN * 2, BB * NN * 2,
            DIM, DIM, DIM, DIM, DIM, DIM, DIM, DIM,
            DIM * 3 * DIM, DIM * DIM, DIM,
            DIM * DIM, DIM * DIM, DIM * DIM, DIM * DIM, DIM,
            DIM * 4 * DIM, 4 * DIM, 4 * DIM * DIM, DIM};
        float sentinel = 0.0f;
        if (n_in != 24) sentinel = 2000.0f;
        else {
            for (int i = 0; i < 24; i++)
                if (in_sizes[i] != expect[i]) { sentinel = 1000.0f + i; break; }
        }
        if (sentinel == 0.0f && ws_size < WS_NEED) sentinel = 3000.0f;
        if (sentinel == 0.0f && out_size != (int)(2 * SZ)) sentinel = 4000.0f;
        if (sentinel != 0.0f) {
            fill_f32<<<(int)((SZ + 255) / 256), 256, 0, stream>>>(out, sentinel, (int)SZ);
            return;
        }
    }

    float* bufX = (float*)d_ws;
    ushort_t* bufAb = (ushort_t*)(bufX + SZ);        // SZ bf16
    ushort_t* bufQKVb = bufAb + SZ;                  // 4*SZ bf16
    ushort_t* wts = bufQKVb + 4 * SZ;

    ushort_t* qkvT = wts;                            // [2304][768]
    ushort_t* apT  = qkvT + 2304 * 768;
    ushort_t* pqT  = apT + 768 * 768;
    ushort_t* pkT  = pqT + 768 * 768;                // pkT||pvT = [1536][768]
    ushort_t* pvT  = pkT + 768 * 768;
    ushort_t* cpT  = pvT + 768 * 768;
    ushort_t* fc1T = cpT + 768 * 768;                // [3072][768]
    ushort_t* fc2T = fc1T + 3072 * 768;              // [768][3072]
    ushort_t* HID  = bufQKVb;                        // [8192][3072] (MLP phase)

    // ---- one-time weight cast+transpose ----
    XArgs xa;
    xa.src[0] = qkv_w;        xa.dst[0] = qkvT; xa.K[0] = 768;  xa.N[0] = 2304;
    xa.src[1] = attn_proj_w;  xa.dst[1] = apT;  xa.K[1] = 768;  xa.N[1] = 768;
    xa.src[2] = projq_w;      xa.dst[2] = pqT;  xa.K[2] = 768;  xa.N[2] = 768;
    xa.src[3] = projk_w;      xa.dst[3] = pkT;  xa.K[3] = 768;  xa.N[3] = 768;
    xa.src[4] = projv_w;      xa.dst[4] = pvT;  xa.K[4] = 768;  xa.N[4] = 768;
    xa.src[5] = cross_proj_w; xa.dst[5] = cpT;  xa.K[5] = 768;  xa.N[5] = 768;
    xa.src[6] = fc1_w;        xa.dst[6] = fc1T; xa.K[6] = 768;  xa.N[6] = 3072;
    xa.src[7] = fc2_w;        xa.dst[7] = fc2T; xa.K[7] = 3072; xa.N[7] = 768;
    int acc_t = 0;
    for (int i = 0; i < 8; i++) {
        xa.tstart[i] = acc_t;
        acc_t += (xa.K[i] / 32) * (xa.N[i] / 32);
    }
    xa.tstart[8] = acc_t;  // 9216
    xform_w<<<acc_t, 256, 0, stream>>>(xa);

    const int rt = ROWS * HEADS * 32;               // 3145728
    const int attnGrid = BB * HEADS * (NN / 64);    // 1536
    ushort_t* VTg;

    // ---- self attention ----
    ln_bf16<<<ROWS, 256, 0, stream>>>(x, norm1_g, norm1_b, bufAb);
    gemm_mfma<0, 1><<<64 * 18, 256, 0, stream>>>(bufAb, qkvT, nullptr, nullptr,
                                                 bufQKVb, ROWS, 2304, 768);
    rope2_bf16<<<2 * rt / 256, 256, 0, stream>>>(bufQKVb, xpos, 2304,
                                                 bufQKVb + DIM, xpos, 2304, rt);
    VTg = bufQKVb + 3 * SZ;  // qkv occupies 3*SZ; VT in 4th quarter
    transpose_v<<<attnGrid, 256, 0, stream>>>(bufQKVb + 2 * DIM, 2304, VTg);
    attn_mfma<<<attnGrid, 256, 0, stream>>>(bufQKVb, 2304, bufQKVb + DIM, 2304,
                                            VTg, bufAb, DIM);
    gemm_mfma<0, 0><<<64 * 6, 256, 0, stream>>>(bufAb, apT, attn_proj_b, x,
                                                bufX, ROWS, 768, 768);

    // ---- cross attention ----
    ushort_t* Qc = bufQKVb;                         // [8192][768]
    ushort_t* KVc = bufQKVb + SZ;                   // [8192][1536]: K | V
    ln_bf16<<<ROWS, 256, 0, stream>>>(bufX, norm2_g, norm2_b, bufAb);
    gemm_mfma<0, 1><<<64 * 6, 256, 0, stream>>>(bufAb, pqT, nullptr, nullptr,
                                                Qc, ROWS, 768, 768);
    ln_bf16<<<ROWS, 256, 0, stream>>>(y, normy_g, normy_b, bufAb);
    gemm_mfma<0, 1><<<64 * 12, 256, 0, stream>>>(bufAb, pkT, nullptr, nullptr,
                                                 KVc, ROWS, 1536, 768);
    rope2_bf16<<<2 * rt / 256, 256, 0, stream>>>(Qc, xpos, 768,
                                                 KVc, ypos, 1536, rt);
    VTg = bufQKVb + 3 * SZ;
    transpose_v<<<attnGrid, 256, 0, stream>>>(KVc + DIM, 1536, VTg);
    attn_mfma<<<attnGrid, 256, 0, stream>>>(Qc, 768, KVc, 1536, VTg, bufAb, DIM);
    gemm_mfma<0, 0><<<64 * 6, 256, 0, stream>>>(bufAb, cpT, cross_proj_b, bufX,
                                                bufX, ROWS, 768, 768);

    // ---- MLP ----
    ln_bf16<<<ROWS, 256, 0, stream>>>(bufX, norm3_g, norm3_b, bufAb);
    gemm_mfma<1, 1><<<64 * 24, 256, 0, stream>>>(bufAb, fc1T, fc1_b, nullptr,
                                                 HID, ROWS, 3072, 768);
    gemm_mfma<0, 0><<<64 * 6, 256, 0, stream>>>(HID, fc2T, fc2_b, bufX,
                                                out, ROWS, 768, 3072);

    // ---- output y passthrough ----
    hipMemcpyAsync(out + SZ, y, SZ * sizeof(float), hipMemcpyDeviceToDevice, stream);
}

// Round 9
// 613.244 us; speedup vs baseline: 28.7514x; 1.0552x over previous
//
#include <hip/hip_runtime.h>
#include <hip/hip_bf16.h>
#include <math.h>

#define DIM 768
#define HEADS 12
#define HD 64
#define BB 8
#define NN 1024
#define EPSV 1e-5f

typedef unsigned int uint32;
typedef unsigned short ushort_t;
using short8 = __attribute__((ext_vector_type(8))) short;
using f32x4 = __attribute__((ext_vector_type(4))) float;

static __device__ inline ushort_t f2b(float v) {  // fp32 -> bf16 RNE
    uint32 u = __float_as_uint(v);
    return (ushort_t)((u + 0x7FFFu + ((u >> 16) & 1u)) >> 16);
}
static __device__ inline float b2f(ushort_t v) {
    return __uint_as_float((uint32)v << 16);
}

// async global->LDS, 16B per lane; LDS dest is wave-uniform base + lane*16
static __device__ __forceinline__ void gload_lds16(const ushort_t* g, ushort_t* l) {
    __builtin_amdgcn_global_load_lds(
        (const __attribute__((address_space(1))) void*)g,
        (__attribute__((address_space(3))) void*)l, 16, 0, 0);
}

// ---------------- LayerNorm -> bf16: one block (256 thr) per row of 768 ---------
__global__ __launch_bounds__(256) void ln_bf16(const float* __restrict__ in,
                                               const float* __restrict__ g,
                                               const float* __restrict__ b,
                                               ushort_t* __restrict__ out) {
    int r = blockIdx.x;
    const float* x = in + (size_t)r * DIM;
    ushort_t* o = out + (size_t)r * DIM;
    int t = threadIdx.x;
    float v0 = x[t], v1 = x[t + 256], v2 = x[t + 512];
    float s = v0 + v1 + v2;
    float s2 = v0 * v0 + v1 * v1 + v2 * v2;
    for (int off = 32; off; off >>= 1) {
        s += __shfl_xor(s, off);
        s2 += __shfl_xor(s2, off);
    }
    __shared__ float ls[4], lq[4];
    int wid = t >> 6;
    if ((t & 63) == 0) { ls[wid] = s; lq[wid] = s2; }
    __syncthreads();
    s = ls[0] + ls[1] + ls[2] + ls[3];
    s2 = lq[0] + lq[1] + lq[2] + lq[3];
    float mean = s * (1.0f / DIM);
    float var = s2 * (1.0f / DIM) - mean * mean;
    float rs = rsqrtf(var + EPSV);
    o[t]       = f2b((v0 - mean) * rs * g[t]       + b[t]);
    o[t + 256] = f2b((v1 - mean) * rs * g[t + 256] + b[t + 256]);
    o[t + 512] = f2b((v2 - mean) * rs * g[t + 512] + b[t + 512]);
}

// ---------------- Weight cast+transpose: W[K][N] fp32 -> Wt[N][K] bf16 ----------
struct XArgs {
    const float* src[8];
    ushort_t* dst[8];
    int K[8], N[8];
    int tstart[9];
};
__global__ __launch_bounds__(256) void xform_w(XArgs a) {
    __shared__ float tl[32][33];
    int t = blockIdx.x;
    int w = 0;
    while (t >= a.tstart[w + 1]) w++;
    int lt = t - a.tstart[w];
    int ntn = a.N[w] >> 5;
    int k0 = (lt / ntn) * 32, n0 = (lt % ntn) * 32;
    const float* src = a.src[w];
    ushort_t* dst = a.dst[w];
    int K = a.K[w], N = a.N[w];
    int rr = threadIdx.x >> 5, cc = threadIdx.x & 31;
#pragma unroll
    for (int u = 0; u < 4; u++)
        tl[rr + u * 8][cc] = src[(size_t)(k0 + rr + u * 8) * N + n0 + cc];
    __syncthreads();
#pragma unroll
    for (int u = 0; u < 4; u++)
        dst[(size_t)(n0 + rr + u * 8) * K + k0 + cc] = f2b(tl[cc][rr + u * 8]);
}

// ---------------- bf16 MFMA GEMM: global_load_lds + swizzled LDS ----------------
// C[M,N] = A[M,K] @ Wt[N,K]^T. 128x128 tile, BK=64, 4 waves (2x2).
// LDS linear [128][64] per operand; chunk (16B) swizzle: slot c' holds logical
// chunk c'^(row&7); DMA source pre-applies the inverse, reads apply it again.
template <int ACT, int OBF16>
__global__ __launch_bounds__(256) void gemm_mfma(const ushort_t* __restrict__ A,
                                                 const ushort_t* __restrict__ Wt,
                                                 const float* __restrict__ bias,
                                                 const float* res,
                                                 void* Cout, int M, int N, int K) {
    __shared__ ushort_t As[128 * 64];
    __shared__ ushort_t Bs[128 * 64];
    int nblk = N >> 7;
    int nwg = (M >> 7) * nblk;              // always divisible by 8 here
    int bid = blockIdx.x;
    int wg = (bid & 7) * (nwg >> 3) + (bid >> 3);  // bijective XCD swizzle
    int bx = wg % nblk, by = wg / nblk;
    int m0 = by * 128, n0 = bx * 128;
    int tid = threadIdx.x;
    int wid = tid >> 6, lane = tid & 63;
    int wm = wid >> 1, wn = wid & 1;
    int l15 = lane & 15, lh = lane >> 4;

    // staging geometry: chunk_id = (wid*4+inst)*64 + lane; row=id>>3, cslot=id&7
    int srow0 = wid * 32 + (lane >> 3);
    int cslot = lane & 7;

    f32x4 acc[4][4] = {};
    for (int k0 = 0; k0 < K; k0 += 64) {
        __syncthreads();                    // prev-iter LDS reads complete
#pragma unroll
        for (int inst = 0; inst < 4; inst++) {
            int r = srow0 + inst * 8;
            int csrc = (cslot ^ (r & 7)) << 3;
            gload_lds16(A + (size_t)(m0 + r) * K + k0 + csrc,
                        &As[(wid * 4 + inst) * 512]);
            gload_lds16(Wt + (size_t)(n0 + r) * K + k0 + csrc,
                        &Bs[(wid * 4 + inst) * 512]);
        }
        __syncthreads();                    // vmcnt(0) drain + barrier

#pragma unroll
        for (int ks8 = 0; ks8 < 2; ks8++) {
            int cA = ks8 * 4 + lh;
            short8 af[4], bfr[4];
#pragma unroll
            for (int i = 0; i < 4; i++) {
                int rA = wm * 64 + i * 16 + l15;
                af[i] = *(const short8*)&As[rA * 64 + ((cA ^ (rA & 7)) << 3)];
                int rB = wn * 64 + i * 16 + l15;
                bfr[i] = *(const short8*)&Bs[rB * 64 + ((cA ^ (rB & 7)) << 3)];
            }
#pragma unroll
            for (int i = 0; i < 4; i++)
#pragma unroll
                for (int j = 0; j < 4; j++)
                    acc[i][j] = __builtin_amdgcn_mfma_f32_16x16x32_bf16(
                        af[i], bfr[j], acc[i][j], 0, 0, 0);
        }
    }

    // epilogue: C/D layout col=lane&15, row=(lane>>4)*4+reg
    int col = l15, rg = lh * 4;
#pragma unroll
    for (int j = 0; j < 4; j++) {
        int n = n0 + wn * 64 + j * 16 + col;
        float bv = bias ? bias[n] : 0.0f;
#pragma unroll
        for (int i = 0; i < 4; i++) {
#pragma unroll
            for (int r = 0; r < 4; r++) {
                int m = m0 + wm * 64 + i * 16 + rg + r;
                float v = acc[i][j][r] + bv;
                if (ACT == 1) v = 0.5f * v * (1.0f + erff(v * 0.70710678118654752f));
                if (res) v += res[(size_t)m * N + n];
                if (OBF16) ((ushort_t*)Cout)[(size_t)m * N + n] = f2b(v);
                else       ((float*)Cout)[(size_t)m * N + n] = v;
            }
        }
    }
}

// ---------------- RoPE2D x2 streams, in place on bf16 ---------------------------
__global__ __launch_bounds__(256) void rope2_bf16(ushort_t* __restrict__ ta,
                                                  const int* __restrict__ pa, int sa,
                                                  ushort_t* __restrict__ tb,
                                                  const int* __restrict__ pb, int sb,
                                                  int rt) {
    int idx = blockIdx.x * 256 + threadIdx.x;
    ushort_t* t;
    const int* pos;
    int rowStride;
    if (idx >= rt) { idx -= rt; t = tb; pos = pb; rowStride = sb; }
    else           { t = ta; pos = pa; rowStride = sa; }
    int i = idx & 15;
    int half = (idx >> 4) & 1;
    int h = (idx >> 5) % HEADS;
    int bn = idx / (HEADS * 32);
    int p = pos[(size_t)bn * 2 + half];
    float inv = powf(100.0f, -(float)i / 16.0f);
    float f = (float)p * inv;
    float c, s;
    sincosf(f, &s, &c);
    ushort_t* base = t + (size_t)bn * rowStride + h * HD + half * 32;
    float t1 = b2f(base[i]), t2 = b2f(base[i + 16]);
    base[i]      = f2b(t1 * c - t2 * s);
    base[i + 16] = f2b(t2 * c + t1 * s);
}

// ---------------- V global transpose: [b][n][h*64+d] -> VT[b][h][d][n] ----------
__global__ __launch_bounds__(256) void transpose_v(const ushort_t* __restrict__ src,
                                                   int ss, ushort_t* __restrict__ dst) {
    __shared__ ushort_t tl[64][66];
    int bid = blockIdx.x;       // b*HEADS*16 + h*16 + nt
    int nt = bid & 15;
    int h = (bid >> 4) % HEADS;
    int b = bid / (16 * HEADS);
    int n0 = nt * 64;
    int t = threadIdx.x;
    int r = t >> 2, c0 = (t & 3) * 16;
    const ushort_t* s = src + ((size_t)(b * NN) + n0 + r) * ss + h * HD + c0;
    *(uint4*)&tl[r][c0]     = *(const uint4*)s;
    *(uint4*)&tl[r][c0 + 8] = *(const uint4*)(s + 8);
    __syncthreads();
    ushort_t* d = dst + (((size_t)(b * HEADS + h)) * HD + r) * NN + n0 + c0;
    ushort_t tmp[16];
#pragma unroll
    for (int u = 0; u < 16; u++) tmp[u] = tl[c0 + u][r];
    *(uint4*)d       = *(uint4*)tmp;
    *(uint4*)(d + 8) = *(uint4*)(tmp + 8);
}

// ---------------- MFMA flash attention (bf16), V^T input, K/V prefetch ----------
__global__ __launch_bounds__(256) void attn_mfma(const ushort_t* __restrict__ Q, int sq,
                                                 const ushort_t* __restrict__ K, int sk,
                                                 const ushort_t* __restrict__ VT,
                                                 ushort_t* __restrict__ O, int so) {
    __shared__ ushort_t Qs[64][72];
    __shared__ ushort_t Ks[64][72];
    __shared__ ushort_t Vs[64][72];
    __shared__ ushort_t Ps[64][72];

    int bid = blockIdx.x;
    int qb = bid & 15;
    int h = (bid >> 4) % HEADS;
    int b = bid / (16 * HEADS);
    int n0 = qb * 64;

    int tid = threadIdx.x;
    int lane = tid & 63, wq = tid >> 6;
    int l15 = lane & 15, lh = lane >> 4;

    const ushort_t* Qbase = Q + (size_t)b * NN * sq + h * HD;
    const ushort_t* Kbase = K + (size_t)b * NN * sk + h * HD;
    const ushort_t* VTbase = VT + ((size_t)(b * HEADS + h)) * HD * NN;
    ushort_t* Obase = O + (size_t)b * NN * so + h * HD;

    int row = tid >> 2, c0 = (tid & 3) * 16;
    {
        const ushort_t* src = Qbase + (size_t)(n0 + row) * sq + c0;
        *(uint4*)&Qs[row][c0]     = *(const uint4*)src;
        *(uint4*)&Qs[row][c0 + 8] = *(const uint4*)(src + 8);
    }

    const ushort_t* kp = Kbase + (size_t)row * sk + c0;
    const ushort_t* vp = VTbase + (size_t)row * NN + c0;
    uint4 rk0 = *(const uint4*)kp, rk1 = *(const uint4*)(kp + 8);
    uint4 rv0 = *(const uint4*)vp, rv1 = *(const uint4*)(vp + 8);

    f32x4 oacc[4] = {};
    float mrow[4] = {-1e30f, -1e30f, -1e30f, -1e30f};
    float lrow[4] = {};

    for (int kt = 0; kt < NN / 64; kt++) {
        __syncthreads();
        *(uint4*)&Ks[row][c0]     = rk0;
        *(uint4*)&Ks[row][c0 + 8] = rk1;
        *(uint4*)&Vs[row][c0]     = rv0;
        *(uint4*)&Vs[row][c0 + 8] = rv1;
        __syncthreads();
        if (kt + 1 < NN / 64) {
            const ushort_t* kp2 = kp + (size_t)(kt + 1) * 64 * sk;
            const ushort_t* vp2 = vp + (size_t)(kt + 1) * 64;
            rk0 = *(const uint4*)kp2;
            rk1 = *(const uint4*)(kp2 + 8);
            rv0 = *(const uint4*)vp2;
            rv1 = *(const uint4*)(vp2 + 8);
        }

        f32x4 s[4] = {};
#pragma unroll
        for (int ks8 = 0; ks8 < 2; ks8++) {
            short8 aq = *(const short8*)&Qs[wq * 16 + l15][ks8 * 32 + lh * 8];
#pragma unroll
            for (int j = 0; j < 4; j++) {
                short8 bk = *(const short8*)&Ks[j * 16 + l15][ks8 * 32 + lh * 8];
                s[j] = __builtin_amdgcn_mfma_f32_16x16x32_bf16(aq, bk, s[j], 0, 0, 0);
            }
        }

        float corr[4];
#pragma unroll
        for (int r = 0; r < 4; r++) {
            float v0 = s[0][r] * 0.125f, v1 = s[1][r] * 0.125f;
            float v2 = s[2][r] * 0.125f, v3 = s[3][r] * 0.125f;
            float rm = fmaxf(fmaxf(v0, v1), fmaxf(v2, v3));
            rm = fmaxf(rm, __shfl_xor(rm, 1));
            rm = fmaxf(rm, __shfl_xor(rm, 2));
            rm = fmaxf(rm, __shfl_xor(rm, 4));
            rm = fmaxf(rm, __shfl_xor(rm, 8));
            float mn = fmaxf(mrow[r], rm);
            corr[r] = __expf(mrow[r] - mn);
            mrow[r] = mn;
            float p0 = __expf(v0 - mn), p1 = __expf(v1 - mn);
            float p2 = __expf(v2 - mn), p3 = __expf(v3 - mn);
            float ps = p0 + p1 + p2 + p3;
            ps += __shfl_xor(ps, 1);
            ps += __shfl_xor(ps, 2);
            ps += __shfl_xor(ps, 4);
            ps += __shfl_xor(ps, 8);
            lrow[r] = lrow[r] * corr[r] + ps;
            int qrow = wq * 16 + lh * 4 + r;
            Ps[qrow][0 * 16 + l15] = f2b(p0);
            Ps[qrow][1 * 16 + l15] = f2b(p1);
            Ps[qrow][2 * 16 + l15] = f2b(p2);
            Ps[qrow][3 * 16 + l15] = f2b(p3);
        }
#pragma unroll
        for (int j = 0; j < 4; j++)
#pragma unroll
            for (int r = 0; r < 4; r++) oacc[j][r] *= corr[r];

#pragma unroll
        for (int ks8 = 0; ks8 < 2; ks8++) {
            short8 ap = *(const short8*)&Ps[wq * 16 + l15][ks8 * 32 + lh * 8];
#pragma unroll
            for (int j = 0; j < 4; j++) {
                short8 bv = *(const short8*)&Vs[j * 16 + l15][ks8 * 32 + lh * 8];
                oacc[j] = __builtin_amdgcn_mfma_f32_16x16x32_bf16(ap, bv, oacc[j], 0, 0, 0);
            }
        }
    }

#pragma unroll
    for (int r = 0; r < 4; r++) {
        float inv = 1.0f / lrow[r];
        int qrow = n0 + wq * 16 + lh * 4 + r;
#pragma unroll
        for (int j = 0; j < 4; j++)
            Obase[(size_t)qrow * so + j * 16 + l15] = f2b(oacc[j][r] * inv);
    }
}

// ---------------- sentinel fill -------------------------------------------------
__global__ __launch_bounds__(256) void fill_f32(float* __restrict__ out, float v, int n) {
    int i = blockIdx.x * 256 + threadIdx.x;
    if (i < n) out[i] = v;
}

extern "C" void kernel_launch(void* const* d_in, const int* in_sizes, int n_in,
                              void* d_out, int out_size, void* d_ws, size_t ws_size,
                              hipStream_t stream) {
    const float* x = (const float*)d_in[0];
    const float* y = (const float*)d_in[1];
    const int* xpos = (const int*)d_in[2];
    const int* ypos = (const int*)d_in[3];
    const float* norm1_g = (const float*)d_in[4];
    const float* norm1_b = (const float*)d_in[5];
    const float* norm2_g = (const float*)d_in[6];
    const float* norm2_b = (const float*)d_in[7];
    const float* norm3_g = (const float*)d_in[8];
    const float* norm3_b = (const float*)d_in[9];
    const float* normy_g = (const float*)d_in[10];
    const float* normy_b = (const float*)d_in[11];
    const float* qkv_w = (const float*)d_in[12];
    const float* attn_proj_w = (const float*)d_in[13];
    const float* attn_proj_b = (const float*)d_in[14];
    const float* projq_w = (const float*)d_in[15];
    const float* projk_w = (const float*)d_in[16];
    const float* projv_w = (const float*)d_in[17];
    const float* cross_proj_w = (const float*)d_in[18];
    const float* cross_proj_b = (const float*)d_in[19];
    const float* fc1_w = (const float*)d_in[20];
    const float* fc1_b = (const float*)d_in[21];
    const float* fc2_w = (const float*)d_in[22];
    const float* fc2_b = (const float*)d_in[23];
    float* out = (float*)d_out;

    const size_t SZ = (size_t)BB * NN * DIM;  // 6291456
    const int ROWS = BB * NN;                 // 8192

    const size_t WS_NEED = SZ * 4 + SZ * 2 + 4 * SZ * 2 + 9437184ull * 2;  // ~107 MB

    {   // ---- interface sentinels ----
        const int expect[24] = {
            (int)SZ, (int)SZ, BB * NN * 2, BB * NN * 2,
            DIM, DIM, DIM, DIM, DIM, DIM, DIM, DIM,
            DIM * 3 * DIM, DIM * DIM, DIM,
            DIM * DIM, DIM * DIM, DIM * DIM, DIM * DIM, DIM,
            DIM * 4 * DIM, 4 * DIM, 4 * DIM * DIM, DIM};
        float sentinel = 0.0f;
        if (n_in != 24) sentinel = 2000.0f;
        else {
            for (int i = 0; i < 24; i++)
                if (in_sizes[i] != expect[i]) { sentinel = 1000.0f + i; break; }
        }
        if (sentinel == 0.0f && ws_size < WS_NEED) sentinel = 3000.0f;
        if (sentinel == 0.0f && out_size != (int)(2 * SZ)) sentinel = 4000.0f;
        if (sentinel != 0.0f) {
            fill_f32<<<(int)((SZ + 255) / 256), 256, 0, stream>>>(out, sentinel, (int)SZ);
            return;
        }
    }

    float* bufX = (float*)d_ws;
    ushort_t* bufAb = (ushort_t*)(bufX + SZ);        // SZ bf16
    ushort_t* bufQKVb = bufAb + SZ;                  // 4*SZ bf16
    ushort_t* wts = bufQKVb + 4 * SZ;

    ushort_t* qkvT = wts;                            // [2304][768]
    ushort_t* apT  = qkvT + 2304 * 768;
    ushort_t* pqT  = apT + 768 * 768;
    ushort_t* pkT  = pqT + 768 * 768;                // pkT||pvT = [1536][768]
    ushort_t* pvT  = pkT + 768 * 768;
    ushort_t* cpT  = pvT + 768 * 768;
    ushort_t* fc1T = cpT + 768 * 768;                // [3072][768]
    ushort_t* fc2T = fc1T + 3072 * 768;              // [768][3072]
    ushort_t* HID  = bufQKVb;                        // [8192][3072] (MLP phase)

    // ---- one-time weight cast+transpose ----
    XArgs xa;
    xa.src[0] = qkv_w;        xa.dst[0] = qkvT; xa.K[0] = 768;  xa.N[0] = 2304;
    xa.src[1] = attn_proj_w;  xa.dst[1] = apT;  xa.K[1] = 768;  xa.N[1] = 768;
    xa.src[2] = projq_w;      xa.dst[2] = pqT;  xa.K[2] = 768;  xa.N[2] = 768;
    xa.src[3] = projk_w;      xa.dst[3] = pkT;  xa.K[3] = 768;  xa.N[3] = 768;
    xa.src[4] = projv_w;      xa.dst[4] = pvT;  xa.K[4] = 768;  xa.N[4] = 768;
    xa.src[5] = cross_proj_w; xa.dst[5] = cpT;  xa.K[5] = 768;  xa.N[5] = 768;
    xa.src[6] = fc1_w;        xa.dst[6] = fc1T; xa.K[6] = 768;  xa.N[6] = 3072;
    xa.src[7] = fc2_w;        xa.dst[7] = fc2T; xa.K[7] = 3072; xa.N[7] = 768;
    int acc_t = 0;
    for (int i = 0; i < 8; i++) {
        xa.tstart[i] = acc_t;
        acc_t += (xa.K[i] / 32) * (xa.N[i] / 32);
    }
    xa.tstart[8] = acc_t;  // 9216
    xform_w<<<acc_t, 256, 0, stream>>>(xa);

    const int rt = ROWS * HEADS * 32;               // 3145728
    const int attnGrid = BB * HEADS * (NN / 64);    // 1536
    ushort_t* VTg;

    // ---- self attention ----
    ln_bf16<<<ROWS, 256, 0, stream>>>(x, norm1_g, norm1_b, bufAb);
    gemm_mfma<0, 1><<<64 * 18, 256, 0, stream>>>(bufAb, qkvT, nullptr, nullptr,
                                                 bufQKVb, ROWS, 2304, 768);
    rope2_bf16<<<2 * rt / 256, 256, 0, stream>>>(bufQKVb, xpos, 2304,
                                                 bufQKVb + DIM, xpos, 2304, rt);
    VTg = bufQKVb + 3 * SZ;
    transpose_v<<<attnGrid, 256, 0, stream>>>(bufQKVb + 2 * DIM, 2304, VTg);
    attn_mfma<<<attnGrid, 256, 0, stream>>>(bufQKVb, 2304, bufQKVb + DIM, 2304,
                                            VTg, bufAb, DIM);
    gemm_mfma<0, 0><<<64 * 6, 256, 0, stream>>>(bufAb, apT, attn_proj_b, x,
                                                bufX, ROWS, 768, 768);

    // ---- cross attention ----
    ushort_t* Qc = bufQKVb;                         // [8192][768]
    ushort_t* KVc = bufQKVb + SZ;                   // [8192][1536]: K | V
    ln_bf16<<<ROWS, 256, 0, stream>>>(bufX, norm2_g, norm2_b, bufAb);
    gemm_mfma<0, 1><<<64 * 6, 256, 0, stream>>>(bufAb, pqT, nullptr, nullptr,
                                                Qc, ROWS, 768, 768);
    ln_bf16<<<ROWS, 256, 0, stream>>>(y, normy_g, normy_b, bufAb);
    gemm_mfma<0, 1><<<64 * 12, 256, 0, stream>>>(bufAb, pkT, nullptr, nullptr,
                                                 KVc, ROWS, 1536, 768);
    rope2_bf16<<<2 * rt / 256, 256, 0, stream>>>(Qc, xpos, 768,
                                                 KVc, ypos, 1536, rt);
    VTg = bufQKVb + 3 * SZ;
    transpose_v<<<attnGrid, 256, 0, stream>>>(KVc + DIM, 1536, VTg);
    attn_mfma<<<attnGrid, 256, 0, stream>>>(Qc, 768, KVc, 1536, VTg, bufAb, DIM);
    gemm_mfma<0, 0><<<64 * 6, 256, 0, stream>>>(bufAb, cpT, cross_proj_b, bufX,
                                                bufX, ROWS, 768, 768);

    // ---- MLP ----
    ln_bf16<<<ROWS, 256, 0, stream>>>(bufX, norm3_g, norm3_b, bufAb);
    gemm_mfma<1, 1><<<64 * 24, 256, 0, stream>>>(bufAb, fc1T, fc1_b, nullptr,
                                                 HID, ROWS, 3072, 768);
    gemm_mfma<0, 0><<<64 * 6, 256, 0, stream>>>(HID, fc2T, fc2_b, bufX,
                                                out, ROWS, 768, 3072);

    // ---- output y passthrough ----
    hipMemcpyAsync(out + SZ, y, SZ * sizeof(float), hipMemcpyDeviceToDevice, stream);
}

// Round 10
// 553.644 us; speedup vs baseline: 31.8465x; 1.1076x over previous
//
#include <hip/hip_runtime.h>
#include <hip/hip_bf16.h>
#include <math.h>

#define DIM 768
#define HEADS 12
#define HD 64
#define BB 8
#define NN 1024
#define EPSV 1e-5f

typedef unsigned int uint32;
typedef unsigned short ushort_t;
using short8 = __attribute__((ext_vector_type(8))) short;
using f32x4 = __attribute__((ext_vector_type(4))) float;

static __device__ inline ushort_t f2b(float v) {  // fp32 -> bf16 RNE
    uint32 u = __float_as_uint(v);
    return (ushort_t)((u + 0x7FFFu + ((u >> 16) & 1u)) >> 16);
}
static __device__ inline float b2f(ushort_t v) {
    return __uint_as_float((uint32)v << 16);
}

// async global->LDS, 16B per lane; LDS dest is wave-uniform base + lane*16
static __device__ __forceinline__ void gload_lds16(const ushort_t* g, ushort_t* l) {
    __builtin_amdgcn_global_load_lds(
        (const __attribute__((address_space(1))) void*)g,
        (__attribute__((address_space(3))) void*)l, 16, 0, 0);
}

// ---------------- LayerNorm -> bf16: one block (256 thr) per row of 768 ---------
__global__ __launch_bounds__(256) void ln_bf16(const float* __restrict__ in,
                                               const float* __restrict__ g,
                                               const float* __restrict__ b,
                                               ushort_t* __restrict__ out) {
    int r = blockIdx.x;
    const float* x = in + (size_t)r * DIM;
    ushort_t* o = out + (size_t)r * DIM;
    int t = threadIdx.x;
    float v0 = x[t], v1 = x[t + 256], v2 = x[t + 512];
    float s = v0 + v1 + v2;
    float s2 = v0 * v0 + v1 * v1 + v2 * v2;
    for (int off = 32; off; off >>= 1) {
        s += __shfl_xor(s, off);
        s2 += __shfl_xor(s2, off);
    }
    __shared__ float ls[4], lq[4];
    int wid = t >> 6;
    if ((t & 63) == 0) { ls[wid] = s; lq[wid] = s2; }
    __syncthreads();
    s = ls[0] + ls[1] + ls[2] + ls[3];
    s2 = lq[0] + lq[1] + lq[2] + lq[3];
    float mean = s * (1.0f / DIM);
    float var = s2 * (1.0f / DIM) - mean * mean;
    float rs = rsqrtf(var + EPSV);
    o[t]       = f2b((v0 - mean) * rs * g[t]       + b[t]);
    o[t + 256] = f2b((v1 - mean) * rs * g[t + 256] + b[t + 256]);
    o[t + 512] = f2b((v2 - mean) * rs * g[t + 512] + b[t + 512]);
}

// ---------------- Weight cast+transpose: W[K][N] fp32 -> Wt[N][K] bf16 ----------
struct XArgs {
    const float* src[8];
    ushort_t* dst[8];
    int K[8], N[8];
    int tstart[9];
};
__global__ __launch_bounds__(256) void xform_w(XArgs a) {
    __shared__ float tl[32][33];
    int t = blockIdx.x;
    int w = 0;
    while (t >= a.tstart[w + 1]) w++;
    int lt = t - a.tstart[w];
    int ntn = a.N[w] >> 5;
    int k0 = (lt / ntn) * 32, n0 = (lt % ntn) * 32;
    const float* src = a.src[w];
    ushort_t* dst = a.dst[w];
    int K = a.K[w], N = a.N[w];
    int rr = threadIdx.x >> 5, cc = threadIdx.x & 31;
#pragma unroll
    for (int u = 0; u < 4; u++)
        tl[rr + u * 8][cc] = src[(size_t)(k0 + rr + u * 8) * N + n0 + cc];
    __syncthreads();
#pragma unroll
    for (int u = 0; u < 4; u++)
        dst[(size_t)(n0 + rr + u * 8) * K + k0 + cc] = f2b(tl[cc][rr + u * 8]);
}

// ---------------- bf16 MFMA GEMM: 2-phase dbuf + global_load_lds + swizzle ------
// C[M,N] = A[M,K] @ Wt[N,K]^T. 128x128 tile, BK=64, 4 waves (2x2).
// LDS linear [128][64] x2 buffers; 16B-chunk swizzle slot c' <-> c'^(row&7).
// Pipeline: STAGE(next) issued BEFORE compute(cur); one __syncthreads per iter
// (its implicit vmcnt(0) lands after compute has covered the load latency).
template <int ACT, int OBF16>
__global__ __launch_bounds__(256) void gemm_mfma(const ushort_t* __restrict__ A,
                                                 const ushort_t* __restrict__ Wt,
                                                 const float* __restrict__ bias,
                                                 const float* res,
                                                 void* Cout, int M, int N, int K) {
    __shared__ ushort_t As[2][128 * 64];
    __shared__ ushort_t Bs[2][128 * 64];
    int nblk = N >> 7;
    int nwg = (M >> 7) * nblk;              // always divisible by 8 here
    int bid = blockIdx.x;
    int wg = (bid & 7) * (nwg >> 3) + (bid >> 3);  // bijective XCD swizzle
    int bx = wg % nblk, by = wg / nblk;
    int m0 = by * 128, n0 = bx * 128;
    int tid = threadIdx.x;
    int wid = tid >> 6, lane = tid & 63;
    int wm = wid >> 1, wn = wid & 1;
    int l15 = lane & 15, lh = lane >> 4;

    // staging geometry: chunk_id = (wid*4+inst)*64 + lane; row=id>>3, cslot=id&7
    int srow0 = wid * 32 + (lane >> 3);
    int cslot = lane & 7;

    auto STAGE = [&](int buf, int k0) {
#pragma unroll
        for (int inst = 0; inst < 4; inst++) {
            int r = srow0 + inst * 8;
            int csrc = (cslot ^ (r & 7)) << 3;
            gload_lds16(A + (size_t)(m0 + r) * K + k0 + csrc,
                        &As[buf][(wid * 4 + inst) * 512]);
            gload_lds16(Wt + (size_t)(n0 + r) * K + k0 + csrc,
                        &Bs[buf][(wid * 4 + inst) * 512]);
        }
    };

    STAGE(0, 0);
    f32x4 acc[4][4] = {};
    __syncthreads();                        // prologue drain

    int nT = K >> 6;
    int cur = 0;
    for (int t = 0; t < nT; t++) {
        if (t + 1 < nT) STAGE(cur ^ 1, (t + 1) << 6);   // async, hidden by compute
#pragma unroll
        for (int ks8 = 0; ks8 < 2; ks8++) {
            int cA = ks8 * 4 + lh;
            short8 af[4], bfr[4];
#pragma unroll
            for (int i = 0; i < 4; i++) {
                int rA = wm * 64 + i * 16 + l15;
                af[i] = *(const short8*)&As[cur][rA * 64 + ((cA ^ (rA & 7)) << 3)];
                int rB = wn * 64 + i * 16 + l15;
                bfr[i] = *(const short8*)&Bs[cur][rB * 64 + ((cA ^ (rB & 7)) << 3)];
            }
#pragma unroll
            for (int i = 0; i < 4; i++)
#pragma unroll
                for (int j = 0; j < 4; j++)
                    acc[i][j] = __builtin_amdgcn_mfma_f32_16x16x32_bf16(
                        af[i], bfr[j], acc[i][j], 0, 0, 0);
        }
        __syncthreads();                    // vmcnt drain (late) + read-done barrier
        cur ^= 1;
    }

    // epilogue: C/D layout col=lane&15, row=(lane>>4)*4+reg
    int col = l15, rg = lh * 4;
#pragma unroll
    for (int j = 0; j < 4; j++) {
        int n = n0 + wn * 64 + j * 16 + col;
        float bv = bias ? bias[n] : 0.0f;
#pragma unroll
        for (int i = 0; i < 4; i++) {
#pragma unroll
            for (int r = 0; r < 4; r++) {
                int m = m0 + wm * 64 + i * 16 + rg + r;
                float v = acc[i][j][r] + bv;
                if (ACT == 1) v = 0.5f * v * (1.0f + erff(v * 0.70710678118654752f));
                if (res) v += res[(size_t)m * N + n];
                if (OBF16) ((ushort_t*)Cout)[(size_t)m * N + n] = f2b(v);
                else       ((float*)Cout)[(size_t)m * N + n] = v;
            }
        }
    }
}

// ---------------- RoPE2D x2 streams, in place on bf16 ---------------------------
__global__ __launch_bounds__(256) void rope2_bf16(ushort_t* __restrict__ ta,
                                                  const int* __restrict__ pa, int sa,
                                                  ushort_t* __restrict__ tb,
                                                  const int* __restrict__ pb, int sb,
                                                  int rt) {
    int idx = blockIdx.x * 256 + threadIdx.x;
    ushort_t* t;
    const int* pos;
    int rowStride;
    if (idx >= rt) { idx -= rt; t = tb; pos = pb; rowStride = sb; }
    else           { t = ta; pos = pa; rowStride = sa; }
    int i = idx & 15;
    int half = (idx >> 4) & 1;
    int h = (idx >> 5) % HEADS;
    int bn = idx / (HEADS * 32);
    int p = pos[(size_t)bn * 2 + half];
    float inv = powf(100.0f, -(float)i / 16.0f);
    float f = (float)p * inv;
    float c, s;
    sincosf(f, &s, &c);
    ushort_t* base = t + (size_t)bn * rowStride + h * HD + half * 32;
    float t1 = b2f(base[i]), t2 = b2f(base[i + 16]);
    base[i]      = f2b(t1 * c - t2 * s);
    base[i + 16] = f2b(t2 * c + t1 * s);
}

// ---------------- V global transpose: [b][n][h*64+d] -> VT[b][h][d][n] ----------
__global__ __launch_bounds__(256) void transpose_v(const ushort_t* __restrict__ src,
                                                   int ss, ushort_t* __restrict__ dst) {
    __shared__ ushort_t tl[64][66];
    int bid = blockIdx.x;       // b*HEADS*16 + h*16 + nt
    int nt = bid & 15;
    int h = (bid >> 4) % HEADS;
    int b = bid / (16 * HEADS);
    int n0 = nt * 64;
    int t = threadIdx.x;
    int r = t >> 2, c0 = (t & 3) * 16;
    const ushort_t* s = src + ((size_t)(b * NN) + n0 + r) * ss + h * HD + c0;
    *(uint4*)&tl[r][c0]     = *(const uint4*)s;
    *(uint4*)&tl[r][c0 + 8] = *(const uint4*)(s + 8);
    __syncthreads();
    ushort_t* d = dst + (((size_t)(b * HEADS + h)) * HD + r) * NN + n0 + c0;
    ushort_t tmp[16];
#pragma unroll
    for (int u = 0; u < 16; u++) tmp[u] = tl[c0 + u][r];
    *(uint4*)d       = *(uint4*)tmp;
    *(uint4*)(d + 8) = *(uint4*)(tmp + 8);
}

// ---------------- MFMA flash attention (bf16), V^T input, K/V prefetch ----------
__global__ __launch_bounds__(256) void attn_mfma(const ushort_t* __restrict__ Q, int sq,
                                                 const ushort_t* __restrict__ K, int sk,
                                                 const ushort_t* __restrict__ VT,
                                                 ushort_t* __restrict__ O, int so) {
    __shared__ ushort_t Qs[64][72];
    __shared__ ushort_t Ks[64][72];
    __shared__ ushort_t Vs[64][72];
    __shared__ ushort_t Ps[64][72];

    int bid = blockIdx.x;
    int qb = bid & 15;
    int h = (bid >> 4) % HEADS;
    int b = bid / (16 * HEADS);
    int n0 = qb * 64;

    int tid = threadIdx.x;
    int lane = tid & 63, wq = tid >> 6;
    int l15 = lane & 15, lh = lane >> 4;

    const ushort_t* Qbase = Q + (size_t)b * NN * sq + h * HD;
    const ushort_t* Kbase = K + (size_t)b * NN * sk + h * HD;
    const ushort_t* VTbase = VT + ((size_t)(b * HEADS + h)) * HD * NN;
    ushort_t* Obase = O + (size_t)b * NN * so + h * HD;

    int row = tid >> 2, c0 = (tid & 3) * 16;
    {
        const ushort_t* src = Qbase + (size_t)(n0 + row) * sq + c0;
        *(uint4*)&Qs[row][c0]     = *(const uint4*)src;
        *(uint4*)&Qs[row][c0 + 8] = *(const uint4*)(src + 8);
    }

    const ushort_t* kp = Kbase + (size_t)row * sk + c0;
    const ushort_t* vp = VTbase + (size_t)row * NN + c0;
    uint4 rk0 = *(const uint4*)kp, rk1 = *(const uint4*)(kp + 8);
    uint4 rv0 = *(const uint4*)vp, rv1 = *(const uint4*)(vp + 8);

    f32x4 oacc[4] = {};
    float mrow[4] = {-1e30f, -1e30f, -1e30f, -1e30f};
    float lrow[4] = {};

    for (int kt = 0; kt < NN / 64; kt++) {
        __syncthreads();
        *(uint4*)&Ks[row][c0]     = rk0;
        *(uint4*)&Ks[row][c0 + 8] = rk1;
        *(uint4*)&Vs[row][c0]     = rv0;
        *(uint4*)&Vs[row][c0 + 8] = rv1;
        __syncthreads();
        if (kt + 1 < NN / 64) {
            const ushort_t* kp2 = kp + (size_t)(kt + 1) * 64 * sk;
            const ushort_t* vp2 = vp + (size_t)(kt + 1) * 64;
            rk0 = *(const uint4*)kp2;
            rk1 = *(const uint4*)(kp2 + 8);
            rv0 = *(const uint4*)vp2;
            rv1 = *(const uint4*)(vp2 + 8);
        }

        f32x4 s[4] = {};
#pragma unroll
        for (int ks8 = 0; ks8 < 2; ks8++) {
            short8 aq = *(const short8*)&Qs[wq * 16 + l15][ks8 * 32 + lh * 8];
#pragma unroll
            for (int j = 0; j < 4; j++) {
                short8 bk = *(const short8*)&Ks[j * 16 + l15][ks8 * 32 + lh * 8];
                s[j] = __builtin_amdgcn_mfma_f32_16x16x32_bf16(aq, bk, s[j], 0, 0, 0);
            }
        }

        float corr[4];
#pragma unroll
        for (int r = 0; r < 4; r++) {
            float v0 = s[0][r] * 0.125f, v1 = s[1][r] * 0.125f;
            float v2 = s[2][r] * 0.125f, v3 = s[3][r] * 0.125f;
            float rm = fmaxf(fmaxf(v0, v1), fmaxf(v2, v3));
            rm = fmaxf(rm, __shfl_xor(rm, 1));
            rm = fmaxf(rm, __shfl_xor(rm, 2));
            rm = fmaxf(rm, __shfl_xor(rm, 4));
            rm = fmaxf(rm, __shfl_xor(rm, 8));
            float mn = fmaxf(mrow[r], rm);
            corr[r] = __expf(mrow[r] - mn);
            mrow[r] = mn;
            float p0 = __expf(v0 - mn), p1 = __expf(v1 - mn);
            float p2 = __expf(v2 - mn), p3 = __expf(v3 - mn);
            float ps = p0 + p1 + p2 + p3;
            ps += __shfl_xor(ps, 1);
            ps += __shfl_xor(ps, 2);
            ps += __shfl_xor(ps, 4);
            ps += __shfl_xor(ps, 8);
            lrow[r] = lrow[r] * corr[r] + ps;
            int qrow = wq * 16 + lh * 4 + r;
            Ps[qrow][0 * 16 + l15] = f2b(p0);
            Ps[qrow][1 * 16 + l15] = f2b(p1);
            Ps[qrow][2 * 16 + l15] = f2b(p2);
            Ps[qrow][3 * 16 + l15] = f2b(p3);
        }
#pragma unroll
        for (int j = 0; j < 4; j++)
#pragma unroll
            for (int r = 0; r < 4; r++) oacc[j][r] *= corr[r];

#pragma unroll
        for (int ks8 = 0; ks8 < 2; ks8++) {
            short8 ap = *(const short8*)&Ps[wq * 16 + l15][ks8 * 32 + lh * 8];
#pragma unroll
            for (int j = 0; j < 4; j++) {
                short8 bv = *(const short8*)&Vs[j * 16 + l15][ks8 * 32 + lh * 8];
                oacc[j] = __builtin_amdgcn_mfma_f32_16x16x32_bf16(ap, bv, oacc[j], 0, 0, 0);
            }
        }
    }

#pragma unroll
    for (int r = 0; r < 4; r++) {
        float inv = 1.0f / lrow[r];
        int qrow = n0 + wq * 16 + lh * 4 + r;
#pragma unroll
        for (int j = 0; j < 4; j++)
            Obase[(size_t)qrow * so + j * 16 + l15] = f2b(oacc[j][r] * inv);
    }
}

// ---------------- sentinel fill -------------------------------------------------
__global__ __launch_bounds__(256) void fill_f32(float* __restrict__ out, float v, int n) {
    int i = blockIdx.x * 256 + threadIdx.x;
    if (i < n) out[i] = v;
}

extern "C" void kernel_launch(void* const* d_in, const int* in_sizes, int n_in,
                              void* d_out, int out_size, void* d_ws, size_t ws_size,
                              hipStream_t stream) {
    const float* x = (const float*)d_in[0];
    const float* y = (const float*)d_in[1];
    const int* xpos = (const int*)d_in[2];
    const int* ypos = (const int*)d_in[3];
    const float* norm1_g = (const float*)d_in[4];
    const float* norm1_b = (const float*)d_in[5];
    const float* norm2_g = (const float*)d_in[6];
    const float* norm2_b = (const float*)d_in[7];
    const float* norm3_g = (const float*)d_in[8];
    const float* norm3_b = (const float*)d_in[9];
    const float* normy_g = (const float*)d_in[10];
    const float* normy_b = (const float*)d_in[11];
    const float* qkv_w = (const float*)d_in[12];
    const float* attn_proj_w = (const float*)d_in[13];
    const float* attn_proj_b = (const float*)d_in[14];
    const float* projq_w = (const float*)d_in[15];
    const float* projk_w = (const float*)d_in[16];
    const float* projv_w = (const float*)d_in[17];
    const float* cross_proj_w = (const float*)d_in[18];
    const float* cross_proj_b = (const float*)d_in[19];
    const float* fc1_w = (const float*)d_in[20];
    const float* fc1_b = (const float*)d_in[21];
    const float* fc2_w = (const float*)d_in[22];
    const float* fc2_b = (const float*)d_in[23];
    float* out = (float*)d_out;

    const size_t SZ = (size_t)BB * NN * DIM;  // 6291456
    const int ROWS = BB * NN;                 // 8192

    const size_t WS_NEED = SZ * 4 + SZ * 2 + 4 * SZ * 2 + 9437184ull * 2;  // ~107 MB

    {   // ---- interface sentinels ----
        const int expect[24] = {
            (int)SZ, (int)SZ, BB * NN * 2, BB * NN * 2,
            DIM, DIM, DIM, DIM, DIM, DIM, DIM, DIM,
            DIM * 3 * DIM, DIM * DIM, DIM,
            DIM * DIM, DIM * DIM, DIM * DIM, DIM * DIM, DIM,
            DIM * 4 * DIM, 4 * DIM, 4 * DIM * DIM, DIM};
        float sentinel = 0.0f;
        if (n_in != 24) sentinel = 2000.0f;
        else {
            for (int i = 0; i < 24; i++)
                if (in_sizes[i] != expect[i]) { sentinel = 1000.0f + i; break; }
        }
        if (sentinel == 0.0f && ws_size < WS_NEED) sentinel = 3000.0f;
        if (sentinel == 0.0f && out_size != (int)(2 * SZ)) sentinel = 4000.0f;
        if (sentinel != 0.0f) {
            fill_f32<<<(int)((SZ + 255) / 256), 256, 0, stream>>>(out, sentinel, (int)SZ);
            return;
        }
    }

    float* bufX = (float*)d_ws;
    ushort_t* bufAb = (ushort_t*)(bufX + SZ);        // SZ bf16
    ushort_t* bufQKVb = bufAb + SZ;                  // 4*SZ bf16
    ushort_t* wts = bufQKVb + 4 * SZ;

    ushort_t* qkvT = wts;                            // [2304][768]
    ushort_t* apT  = qkvT + 2304 * 768;
    ushort_t* pqT  = apT + 768 * 768;
    ushort_t* pkT  = pqT + 768 * 768;                // pkT||pvT = [1536][768]
    ushort_t* pvT  = pkT + 768 * 768;
    ushort_t* cpT  = pvT + 768 * 768;
    ushort_t* fc1T = cpT + 768 * 768;                // [3072][768]
    ushort_t* fc2T = fc1T + 3072 * 768;              // [768][3072]
    ushort_t* HID  = bufQKVb;                        // [8192][3072] (MLP phase)

    // ---- one-time weight cast+transpose ----
    XArgs xa;
    xa.src[0] = qkv_w;        xa.dst[0] = qkvT; xa.K[0] = 768;  xa.N[0] = 2304;
    xa.src[1] = attn_proj_w;  xa.dst[1] = apT;  xa.K[1] = 768;  xa.N[1] = 768;
    xa.src[2] = projq_w;      xa.dst[2] = pqT;  xa.K[2] = 768;  xa.N[2] = 768;
    xa.src[3] = projk_w;      xa.dst[3] = pkT;  xa.K[3] = 768;  xa.N[3] = 768;
    xa.src[4] = projv_w;      xa.dst[4] = pvT;  xa.K[4] = 768;  xa.N[4] = 768;
    xa.src[5] = cross_proj_w; xa.dst[5] = cpT;  xa.K[5] = 768;  xa.N[5] = 768;
    xa.src[6] = fc1_w;        xa.dst[6] = fc1T; xa.K[6] = 768;  xa.N[6] = 3072;
    xa.src[7] = fc2_w;        xa.dst[7] = fc2T; xa.K[7] = 3072; xa.N[7] = 768;
    int acc_t = 0;
    for (int i = 0; i < 8; i++) {
        xa.tstart[i] = acc_t;
        acc_t += (xa.K[i] / 32) * (xa.N[i] / 32);
    }
    xa.tstart[8] = acc_t;  // 9216
    xform_w<<<acc_t, 256, 0, stream>>>(xa);

    const int rt = ROWS * HEADS * 32;               // 3145728
    const int attnGrid = BB * HEADS * (NN / 64);    // 1536
    ushort_t* VTg;

    // ---- self attention ----
    ln_bf16<<<ROWS, 256, 0, stream>>>(x, norm1_g, norm1_b, bufAb);
    gemm_mfma<0, 1><<<64 * 18, 256, 0, stream>>>(bufAb, qkvT, nullptr, nullptr,
                                                 bufQKVb, ROWS, 2304, 768);
    rope2_bf16<<<2 * rt / 256, 256, 0, stream>>>(bufQKVb, xpos, 2304,
                                                 bufQKVb + DIM, xpos, 2304, rt);
    VTg = bufQKVb + 3 * SZ;
    transpose_v<<<attnGrid, 256, 0, stream>>>(bufQKVb + 2 * DIM, 2304, VTg);
    attn_mfma<<<attnGrid, 256, 0, stream>>>(bufQKVb, 2304, bufQKVb + DIM, 2304,
                                            VTg, bufAb, DIM);
    gemm_mfma<0, 0><<<64 * 6, 256, 0, stream>>>(bufAb, apT, attn_proj_b, x,
                                                bufX, ROWS, 768, 768);

    // ---- cross attention ----
    ushort_t* Qc = bufQKVb;                         // [8192][768]
    ushort_t* KVc = bufQKVb + SZ;                   // [8192][1536]: K | V
    ln_bf16<<<ROWS, 256, 0, stream>>>(bufX, norm2_g, norm2_b, bufAb);
    gemm_mfma<0, 1><<<64 * 6, 256, 0, stream>>>(bufAb, pqT, nullptr, nullptr,
                                                Qc, ROWS, 768, 768);
    ln_bf16<<<ROWS, 256, 0, stream>>>(y, normy_g, normy_b, bufAb);
    gemm_mfma<0, 1><<<64 * 12, 256, 0, stream>>>(bufAb, pkT, nullptr, nullptr,
                                                 KVc, ROWS, 1536, 768);
    rope2_bf16<<<2 * rt / 256, 256, 0, stream>>>(Qc, xpos, 768,
                                                 KVc, ypos, 1536, rt);
    VTg = bufQKVb + 3 * SZ;
    transpose_v<<<attnGrid, 256, 0, stream>>>(KVc + DIM, 1536, VTg);
    attn_mfma<<<attnGrid, 256, 0, stream>>>(Qc, 768, KVc, 1536, VTg, bufAb, DIM);
    gemm_mfma<0, 0><<<64 * 6, 256, 0, stream>>>(bufAb, cpT, cross_proj_b, bufX,
                                                bufX, ROWS, 768, 768);

    // ---- MLP ----
    ln_bf16<<<ROWS, 256, 0, stream>>>(bufX, norm3_g, norm3_b, bufAb);
    gemm_mfma<1, 1><<<64 * 24, 256, 0, stream>>>(bufAb, fc1T, fc1_b, nullptr,
                                                 HID, ROWS, 3072, 768);
    gemm_mfma<0, 0><<<64 * 6, 256, 0, stream>>>(HID, fc2T, fc2_b, bufX,
                                                out, ROWS, 768, 3072);

    // ---- output y passthrough ----
    hipMemcpyAsync(out + SZ, y, SZ * sizeof(float), hipMemcpyDeviceToDevice, stream);
}